// Round 9
// baseline (365.214 us; speedup 1.0000x reference)
//
#include <hip/hip_runtime.h>

#define LSEQ 4096
#define DMODEL 1024
#define HTOT 16
#define NAR 8
#define DHEAD 64
#define QKVS 3072  // fused QKV row stride

typedef unsigned short u16;
typedef unsigned int u32;
typedef __attribute__((ext_vector_type(8))) short bf16x8;
typedef __attribute__((ext_vector_type(4))) short bf16x4;
typedef __attribute__((ext_vector_type(4))) float f32x4;
typedef __attribute__((ext_vector_type(4))) unsigned int u32x4;

typedef __attribute__((address_space(1))) void gvoid;
typedef __attribute__((address_space(3))) void lvoid;

__device__ __forceinline__ void cp16(const void* g, void* l) {
    // async global->LDS, 16B per lane; LDS dest = wave-uniform base + lane*16
    __builtin_amdgcn_global_load_lds((gvoid*)(void*)g, (lvoid*)l, 16, 0, 0);
}

// round-to-nearest-even fp32 -> bf16
__device__ __forceinline__ u16 f2bf(float f) {
    u32 x = __float_as_uint(f);
    return (u16)((x + 0x7fffu + ((x >> 16) & 1u)) >> 16);
}
// truncation-pack two fp32 -> packed bf16x2 (1 v_perm_b32)
__device__ __forceinline__ u32 packtr(float lo, float hi) {
    return __builtin_amdgcn_perm(__float_as_uint(hi), __float_as_uint(lo), 0x07060302u);
}

// ---------------------------------------------------------------------------
// X (fp32) -> Xb (bf16, truncated) once.
// ---------------------------------------------------------------------------
__global__ __launch_bounds__(256) void xcast(const float* __restrict__ X, u16* __restrict__ Xb)
{
    const size_t i = (size_t)(blockIdx.x * 256 + threadIdx.x) * 8;
    float4 a0 = *(const float4*)(X + i);
    float4 a1 = *(const float4*)(X + i + 4);
    uint4 pk;
    pk.x = packtr(a0.x, a0.y); pk.y = packtr(a0.z, a0.w);
    pk.z = packtr(a1.x, a1.y); pk.w = packtr(a1.z, a1.w);
    *(uint4*)(Xb + i) = pk;
}

// ---------------------------------------------------------------------------
// Fused transpose of Wq/Wk/Wv: 1024x1024 fp32 -> bf16 (D = S^T), z selects.
// ---------------------------------------------------------------------------
__global__ __launch_bounds__(256) void transp_cvt3(
    const float* __restrict__ Wq, const float* __restrict__ Wk,
    const float* __restrict__ Wv, u16* __restrict__ D)
{
    __shared__ u16 T[64][72];
    const float* S = (blockIdx.z == 0) ? Wq : ((blockIdx.z == 1) ? Wk : Wv);
    u16* Dz = D + (size_t)blockIdx.z * 1024 * 1024;
    const int tid = threadIdx.x;
    const int bx = blockIdx.x, by = blockIdx.y;
#pragma unroll
    for (int i = 0; i < 4; ++i) {
        int id = tid + i * 256;
        int fr = id >> 4, fc = id & 15;
        float4 v = *(const float4*)(S + (size_t)(by * 64 + fr) * 1024 + bx * 64 + fc * 4);
        T[fc * 4 + 0][fr] = f2bf(v.x);
        T[fc * 4 + 1][fr] = f2bf(v.y);
        T[fc * 4 + 2][fr] = f2bf(v.z);
        T[fc * 4 + 3][fr] = f2bf(v.w);
    }
    __syncthreads();
#pragma unroll
    for (int i = 0; i < 2; ++i) {
        int id = tid + i * 256;
        int c = id >> 3, g = id & 7;
        *(uint4*)(Dz + (size_t)(bx * 64 + c) * 1024 + by * 64 + g * 8) = *(const uint4*)&T[c][g * 8];
    }
}

// single-matrix version for Wo
__global__ __launch_bounds__(256) void transp_cvt(
    const float* __restrict__ S, u16* __restrict__ D)
{
    __shared__ u16 T[64][72];
    const int tid = threadIdx.x;
    const int bx = blockIdx.x, by = blockIdx.y;
#pragma unroll
    for (int i = 0; i < 4; ++i) {
        int id = tid + i * 256;
        int fr = id >> 4, fc = id & 15;
        float4 v = *(const float4*)(S + (size_t)(by * 64 + fr) * 1024 + bx * 64 + fc * 4);
        T[fc * 4 + 0][fr] = f2bf(v.x);
        T[fc * 4 + 1][fr] = f2bf(v.y);
        T[fc * 4 + 2][fr] = f2bf(v.z);
        T[fc * 4 + 3][fr] = f2bf(v.w);
    }
    __syncthreads();
#pragma unroll
    for (int i = 0; i < 2; ++i) {
        int id = tid + i * 256;
        int c = id >> 3, g = id & 7;
        *(uint4*)(D + (size_t)(bx * 64 + c) * 1024 + by * 64 + g * 8) = *(const uint4*)&T[c][g * 8];
    }
}

// ---------------------------------------------------------------------------
// QKV = Xb @ [Wq|Wk|Wv]^T(k-major) + FUSED RoPE epilogue. Pure m97 structure.
// ---------------------------------------------------------------------------
__global__ __launch_bounds__(256) void gemm_qkv(
    const u16* __restrict__ A, const u16* __restrict__ Bt, u16* __restrict__ C)
{
    __shared__ u16 As[2][128][32];
    __shared__ u16 Bs[2][128][32];
    const int tid = threadIdx.x;
    const int lane = tid & 63, w = tid >> 6;
    const int col = lane & 15, quad = lane >> 4;
    const int bm = blockIdx.y << 7, bn = blockIdx.x << 7;
    const int wm = (w & 1) << 6, wn = (w >> 1) << 6;
    const int sr = lane >> 2, sc = (lane & 3) << 3;
    const f32x4 zero = {0.f, 0.f, 0.f, 0.f};
    f32x4 acc[4][4];
#pragma unroll
    for (int i = 0; i < 4; ++i)
#pragma unroll
        for (int j = 0; j < 4; ++j) acc[i][j] = zero;

#pragma unroll
    for (int i = 0; i < 2; ++i) {
        const int r0 = w * 32 + i * 16;
        cp16(A  + (size_t)(bm + r0 + sr) * 1024 + sc, &As[0][r0][0]);
        cp16(Bt + (size_t)(bn + r0 + sr) * 1024 + sc, &Bs[0][r0][0]);
    }

    for (int kc = 0; kc < 32; ++kc) {
        const int cur = kc & 1, nxt = cur ^ 1;
        __syncthreads();
        if (kc + 1 < 32) {
            const int k1 = (kc + 1) * 32;
#pragma unroll
            for (int i = 0; i < 2; ++i) {
                const int r0 = w * 32 + i * 16;
                cp16(A  + (size_t)(bm + r0 + sr) * 1024 + k1 + sc, &As[nxt][r0][0]);
                cp16(Bt + (size_t)(bn + r0 + sr) * 1024 + k1 + sc, &Bs[nxt][r0][0]);
            }
        }
        bf16x8 af[4], bfr[4];
#pragma unroll
        for (int i = 0; i < 4; ++i) af[i] = *(const bf16x8*)&As[cur][wm + i * 16 + col][quad * 8];
#pragma unroll
        for (int j = 0; j < 4; ++j) bfr[j] = *(const bf16x8*)&Bs[cur][wn + j * 16 + col][quad * 8];
#pragma unroll
        for (int i = 0; i < 4; ++i)
#pragma unroll
            for (int j = 0; j < 4; ++j)
                acc[i][j] = __builtin_amdgcn_mfma_f32_16x16x32_bf16(af[i], bfr[j], acc[i][j], 0, 0, 0);
    }

    // fused RoPE epilogue (Q and K blocks only)
    if (blockIdx.x < 16) {
        const float scale = (blockIdx.x < 8) ? 0.18033688011112042f : 1.0f;  // Q: (1/8)*log2e
        const float inv0 = __expf((float)col * -0.2878231366242557f);         // irope = col
        const float inv1 = __expf((float)(16 + col) * -0.2878231366242557f);  // irope = 16+col
#pragma unroll
        for (int i = 0; i < 4; ++i)
#pragma unroll
            for (int r = 0; r < 4; ++r) {
                const float t = (float)(bm + wm + i * 16 + quad * 4 + r);
                float s0, c0, s1, c1;
                __sincosf(t * inv0, &s0, &c0);
                __sincosf(t * inv1, &s1, &c1);
                float a0 = acc[i][0][r], b0 = acc[i][2][r];
                acc[i][0][r] = (a0 * c0 - b0 * s0) * scale;
                acc[i][2][r] = (b0 * c0 + a0 * s0) * scale;
                float a1 = acc[i][1][r], b1 = acc[i][3][r];
                acc[i][1][r] = (a1 * c1 - b1 * s1) * scale;
                acc[i][3][r] = (b1 * c1 + a1 * s1) * scale;
            }
    }
#pragma unroll
    for (int i = 0; i < 4; ++i)
#pragma unroll
        for (int j = 0; j < 4; ++j)
#pragma unroll
            for (int r = 0; r < 4; ++r)
                C[(size_t)(bm + wm + i * 16 + quad * 4 + r) * QKVS + bn + wn + j * 16 + col] =
                    f2bf(acc[i][j][r]);
}

// ---------------------------------------------------------------------------
// out = AO @ Wot^T. 128(M)x64(N) tiles, grid 16x32 = 512 blocks (2/CU).
// ---------------------------------------------------------------------------
__global__ __launch_bounds__(256) void gemm_out(
    const u16* __restrict__ A, const u16* __restrict__ Bt, float* __restrict__ C)
{
    __shared__ u16 As[2][128][32];
    __shared__ u16 Bs[2][64][32];
    const int tid = threadIdx.x;
    const int lane = tid & 63, w = tid >> 6;
    const int col = lane & 15, quad = lane >> 4;
    const int bm = blockIdx.y << 7, bn = blockIdx.x << 6;
    const int wm = (w & 1) << 6, wn = (w >> 1) << 5;
    const int sr = lane >> 2, sc = (lane & 3) << 3;
    const f32x4 zero = {0.f, 0.f, 0.f, 0.f};
    f32x4 acc[4][2];
#pragma unroll
    for (int i = 0; i < 4; ++i)
#pragma unroll
        for (int j = 0; j < 2; ++j) acc[i][j] = zero;

    {
#pragma unroll
        for (int i = 0; i < 2; ++i) {
            const int r0 = w * 32 + i * 16;
            cp16(A + (size_t)(bm + r0 + sr) * 1024 + sc, &As[0][r0][0]);
        }
        cp16(Bt + (size_t)(bn + w * 16 + sr) * 1024 + sc, &Bs[0][w * 16][0]);
    }

    for (int kc = 0; kc < 32; ++kc) {
        const int cur = kc & 1, nxt = cur ^ 1;
        __syncthreads();
        if (kc + 1 < 32) {
            const int k1 = (kc + 1) * 32;
#pragma unroll
            for (int i = 0; i < 2; ++i) {
                const int r0 = w * 32 + i * 16;
                cp16(A + (size_t)(bm + r0 + sr) * 1024 + k1 + sc, &As[nxt][r0][0]);
            }
            cp16(Bt + (size_t)(bn + w * 16 + sr) * 1024 + k1 + sc, &Bs[nxt][w * 16][0]);
        }
        bf16x8 af[4], bfr[2];
#pragma unroll
        for (int i = 0; i < 4; ++i) af[i] = *(const bf16x8*)&As[cur][wm + i * 16 + col][quad * 8];
#pragma unroll
        for (int j = 0; j < 2; ++j) bfr[j] = *(const bf16x8*)&Bs[cur][wn + j * 16 + col][quad * 8];
#pragma unroll
        for (int i = 0; i < 4; ++i)
#pragma unroll
            for (int j = 0; j < 2; ++j)
                acc[i][j] = __builtin_amdgcn_mfma_f32_16x16x32_bf16(af[i], bfr[j], acc[i][j], 0, 0, 0);
    }
#pragma unroll
    for (int i = 0; i < 4; ++i)
#pragma unroll
        for (int j = 0; j < 2; ++j)
#pragma unroll
            for (int r = 0; r < 4; ++r)
                C[(size_t)(bm + wm + i * 16 + quad * 4 + r) * 1024 + bn + wn + j * 16 + col] =
                    acc[i][j][r];
}

// ---------------------------------------------------------------------------
// MFMA flash attention v12 — intra-block KV-split, 1024-thread blocks:
//  * Evidence (r3..r8): makespan == longest-chunk-chain x ~6560cyc, invariant
//    to grid decomposition; pipes idle. Fix the CHAIN, not the balance.
//  * Block = (head, q-tile PAIR): 16 waves = 2 q-tiles(wq) x 2 KV-ranges(wkv)
//    x 4 waves. Each wkv-group runs the proven per-chunk pipeline on its own
//    Ks/Vt stream over HALF the chunks. q-pairing makes both halves EQUAL
//    (diff 16/16; causal pair(2i,2i+1) -> (i+1)/(i+1)) -> uniform barriers.
//  * End: wkv1 dumps (O,l) to LDS (overlaying dead K/V), wkv0 adds,
//    normalizes, writes AO. No global scratch / atomics / fences / merge
//    kernel (r4/r6 lessons).
//  * 256 blocks, LDS 100352B -> deterministically 1 block/CU, 4 waves/SIMD,
//    chain <= 16 everywhere by construction.
// ---------------------------------------------------------------------------
__global__ __launch_bounds__(1024) void attn_mfma(
    const u16* __restrict__ QKV, u16* __restrict__ AO)
{
    // per-wkv stream: [0..16384) u16 = Ks[2][128][64]; [16384..25088) = Vt[64][136]
    __shared__ u16 POOL[2][25088];
    const int bid = blockIdx.x;
    int h, pair;
    if (bid < 128) { h = 8 + (bid & 7); pair = bid >> 3; }   // diff pairs
    else { const int j = bid - 128; h = j & 7; pair = j >> 3; } // causal pairs
    const bool causal = (h < NAR);
    const int qt0 = pair * 2;
    const int L = causal ? (pair + 1) : 16;   // equal halves by construction

    const int tid = threadIdx.x;
    const int w = tid >> 6, lane = tid & 63;
    const int wkv = w >> 3;            // KV-range group (0 = merge-writer)
    const int wq = (w >> 2) & 1;       // q-tile within pair
    const int wl = w & 3;              // wave within (wkv, wq)
    const int w8 = w & 7;              // staging role within wkv-group
    const int col = lane & 15, quad = lane >> 4;
    const int qtw = qt0 + wq;
    const int qr0 = qtw * 128 + wl * 32 + col;
    const int qr1 = qr0 + 16;
    const int c0 = wkv * L, c1 = c0 + L;
    // column-permuted position of key a=2*lane (pair b=a+1 at cva+1)
    const int cva = ((lane >> 1) & 3) * 32 + (lane >> 3) * 4 + (lane & 1) * 2;

    u16 (*Ks0)[64] = (u16(*)[64]) & POOL[wkv][0];
    u16 (*Ks1)[64] = (u16(*)[64]) & POOL[wkv][8192];
    u16 (*Vt)[136] = (u16(*)[136]) & POOL[wkv][16384];
    float* LDSX = (float*)&POOL[0][0];          // [256][65] exchange (post-loop overlay)
    float* LDSL = LDSX + 256 * 65;              // [256] l exchange

    // hoisted Q B-frags (rope'd, pre-scaled by 0.125*log2e in gemm_qkv)
    bf16x8 qf[2][2];
#pragma unroll
    for (int s = 0; s < 2; ++s)
#pragma unroll
        for (int ks = 0; ks < 2; ++ks)
            qf[s][ks] = *(const bf16x8*)(QKV + (size_t)(qr0 + s * 16) * QKVS +
                                         h * DHEAD + ks * 32 + quad * 8);

    bf16x8 ones8;
#pragma unroll
    for (int i = 0; i < 8; ++i) ones8[i] = (short)0x3F80;

    const f32x4 zero = {0.f, 0.f, 0.f, 0.f};
    f32x4 O[2][5];  // [set][nd] O^T tiles (d = nd*16+quad*4+r, q = col); nd=4 = l
#pragma unroll
    for (int s = 0; s < 2; ++s)
#pragma unroll
        for (int nd = 0; nd < 5; ++nd) O[s][nd] = zero;

    const int krow = lane >> 3;
    const int kcb = (lane & 7) ^ krow;
    const u16* kbase = QKV + (size_t)krow * QKVS + 1024 + h * DHEAD + kcb * 8;
    const u16* vbase = QKV + (size_t)(lane * 2) * QKVS + 2048 + h * DHEAD + w8 * 8;

    u32x4 vA, vB;               // pending V(ch) dims [w8*8, w8*8+8) for keys 2lane, 2lane+1
    bf16x8 pf8[2][4];           // P(ch) frags: pf8[s][tp] = keys 32tp..32tp+31 (permuted)

#define KSTAGE(DST, CH)                                                                            \
    _Pragma("unroll")                                                                              \
    for (int i = 0; i < 2; ++i) {                                                                  \
        const int rb = i * 8 + w8;                                                                 \
        cp16(kbase + (size_t)((CH) * 128 + rb * 8) * QKVS, &DST[rb * 8][0]);                       \
    }

#define VLOAD(CH)                                                                                  \
    {                                                                                              \
        const u16* vp = vbase + (size_t)(CH) * 128 * QKVS;                                         \
        vA = *(u32x4*)(vp);                                                                        \
        vB = *(u32x4*)(vp + QKVS);                                                                 \
    }

#define VT_WRITE()                                                                                 \
    _Pragma("unroll")                                                                              \
    for (int j = 0; j < 4; ++j) {                                                                  \
        *(u32*)&Vt[w8 * 8 + 2 * j][cva]     = __builtin_amdgcn_perm(vB[j], vA[j], 0x05040100u);    \
        *(u32*)&Vt[w8 * 8 + 2 * j + 1][cva] = __builtin_amdgcn_perm(vB[j], vA[j], 0x07060302u);    \
    }

// PV burst over Vt at K=32: tp-outer, l-row folded in -> acc reuse distance 10.
#define PV_STEP()                                                                                  \
    {                                                                                              \
        __builtin_amdgcn_s_setprio(1);                                                             \
        _Pragma("unroll")                                                                          \
        for (int tp = 0; tp < 4; ++tp) {                                                           \
            bf16x8 vv[4];                                                                          \
            _Pragma("unroll")                                                                      \
            for (int nd = 0; nd < 4; ++nd)                                                         \
                vv[nd] = *(const bf16x8*)&Vt[nd * 16 + col][quad * 32 + tp * 8];                   \
            _Pragma("unroll")                                                                      \
            for (int nd = 0; nd < 4; ++nd) {                                                       \
                O[0][nd] = __builtin_amdgcn_mfma_f32_16x16x32_bf16(vv[nd], pf8[0][tp], O[0][nd], 0, 0, 0); \
                O[1][nd] = __builtin_amdgcn_mfma_f32_16x16x32_bf16(vv[nd], pf8[1][tp], O[1][nd], 0, 0, 0); \
            }                                                                                      \
            O[0][4] = __builtin_amdgcn_mfma_f32_16x16x32_bf16(ones8, pf8[0][tp], O[0][4], 0, 0, 0); \
            O[1][4] = __builtin_amdgcn_mfma_f32_16x16x32_bf16(ones8, pf8[1][tp], O[1][4], 0, 0, 0); \
        }                                                                                          \
        __builtin_amdgcn_s_setprio(0);                                                             \
    }

// S(CH) + exp -> pf8 from Ks buffer KB. ks-outer: st reuse distance 8.
#define S_STEP(KB, CH)                                                                             \
    {                                                                                              \
        const bool mask = causal && ((CH) == qtw);                                                 \
        _Pragma("unroll")                                                                          \
        for (int hf = 0; hf < 2; ++hf) {                                                           \
            f32x4 st[2][4];                                                                        \
            _Pragma("unroll")                                                                      \
            for (int s = 0; s < 2; ++s)                                                            \
                _Pragma("unroll")                                                                  \
                for (int jj = 0; jj < 4; ++jj) st[s][jj] = zero;                                   \
            __builtin_amdgcn_s_setprio(1);                                                         \
            _Pragma("unroll")                                                                      \
            for (int ks = 0; ks < 2; ++ks)                                                         \
                _Pragma("unroll")                                                                  \
                for (int jj = 0; jj < 4; ++jj) {                                                   \
                    bf16x8 kf = *(const bf16x8*)&KB[(hf * 4 + jj) * 16 + col]                      \
                                                  [((ks * 4 + quad) ^ (col & 7)) * 8];             \
                    st[0][jj] = __builtin_amdgcn_mfma_f32_16x16x32_bf16(kf, qf[0][ks], st[0][jj], 0, 0, 0); \
                    st[1][jj] = __builtin_amdgcn_mfma_f32_16x16x32_bf16(kf, qf[1][ks], st[1][jj], 0, 0, 0); \
                }                                                                                  \
            __builtin_amdgcn_s_setprio(0);                                                         \
            if (mask) {                                                                            \
                _Pragma("unroll")                                                                  \
                for (int jj = 0; jj < 4; ++jj) {                                                   \
                    const int kk = (CH) * 128 + (hf * 4 + jj) * 16 + quad * 4;                     \
                    _Pragma("unroll")                                                              \
                    for (int r = 0; r < 4; ++r) {                                                  \
                        if (kk + r > qr0) st[0][jj][r] = -1e30f;                                   \
                        if (kk + r > qr1) st[1][jj][r] = -1e30f;                                   \
                    }                                                                              \
                }                                                                                  \
            }                                                                                      \
            _Pragma("unroll")                                                                      \
            for (int s = 0; s < 2; ++s)                                                            \
                _Pragma("unroll")                                                                  \
                for (int jj = 0; jj < 4; ++jj) {                                                   \
                    u32 plo = packtr(__builtin_amdgcn_exp2f(st[s][jj][0]),                         \
                                     __builtin_amdgcn_exp2f(st[s][jj][1]));                        \
                    u32 phi = packtr(__builtin_amdgcn_exp2f(st[s][jj][2]),                         \
                                     __builtin_amdgcn_exp2f(st[s][jj][3]));                        \
                    u32* p = (u32*)&pf8[s][0] + (hf * 4 + jj) * 2;                                 \
                    p[0] = plo; p[1] = phi;                                                        \
                }                                                                                  \
        }                                                                                          \
    }

    // ---- prologue: stage chunk c0 ----
    KSTAGE(Ks0, c0);
    VLOAD(c0);
    __syncthreads();  // both streams' K(c0) in LDS, V(c0) in regs
    VT_WRITE();       // Vt <- V(c0); visible after next barrier
    if (L > 1) { KSTAGE(Ks1, c0 + 1); }
    if (!causal || c0 <= qtw) { S_STEP(Ks0, c0); }   // pf8 = P(c0)

    // ---- main loop (uniform L iterations across all 16 waves) ----
    for (int it = 1; it < L; ++it) {
        const int ch = c0 + it;
        u16 (*KB)[64] = (it & 1) ? Ks1 : Ks0;
        u16 (*KN)[64] = (it & 1) ? Ks0 : Ks1;
        __syncthreads();  // barrier_a: K(ch) drained; Vt = V(ch-1) visible
        if (it + 1 < L) { KSTAGE(KN, ch + 1); }
        VLOAD(ch);
        if (!causal || (ch - 1) <= qtw) { PV_STEP(); }   // P(ch-1) x V(ch-1)
        if (!causal || ch <= qtw) { S_STEP(KB, ch); }    // pf8 = P(ch)
        __syncthreads();  // barrier_b: all PV reads of Vt done
        VT_WRITE();       // Vt <- V(ch)
    }

    // ---- tail: PV(c1-1) ----
    __syncthreads();  // Vt = V(c1-1) visible
    if (!causal || (c1 - 1) <= qtw) { PV_STEP(); }

    // ---- intra-block merge: wkv1 -> LDS, wkv0 adds + writes AO ----
    __syncthreads();  // all K/V LDS dead; overlay exchange buffer
    const int ql = wq * 128 + wl * 32 + col;
    if (wkv == 1) {
#pragma unroll
        for (int s = 0; s < 2; ++s) {
            const int q = ql + s * 16;
#pragma unroll
            for (int nd = 0; nd < 4; ++nd)
                *(f32x4*)&LDSX[(size_t)q * 65 + nd * 16 + quad * 4] = O[s][nd];
            if (quad == 0) LDSL[q] = O[s][4][0];
        }
    }
    __syncthreads();
    if (wkv == 0) {
#pragma unroll
        for (int s = 0; s < 2; ++s) {
            const int q = ql + s * 16;
            const float l = O[s][4][0] + LDSL[q];
            const float inv = 1.f / l;
            const int qrow = qr0 + s * 16;
#pragma unroll
            for (int nd = 0; nd < 4; ++nd) {
                f32x4 pv = *(const f32x4*)&LDSX[(size_t)q * 65 + nd * 16 + quad * 4];
                ushort4 ov;
                ov.x = f2bf((O[s][nd][0] + pv[0]) * inv);
                ov.y = f2bf((O[s][nd][1] + pv[1]) * inv);
                ov.z = f2bf((O[s][nd][2] + pv[2]) * inv);
                ov.w = f2bf((O[s][nd][3] + pv[3]) * inv);
                *(ushort4*)(AO + (size_t)qrow * 1024 + h * DHEAD + nd * 16 + quad * 4) = ov;
            }
        }
    }
#undef KSTAGE
#undef VLOAD
#undef VT_WRITE
#undef PV_STEP
#undef S_STEP
}

// ---------------------------------------------------------------------------
extern "C" void kernel_launch(void* const* d_in, const int* in_sizes, int n_in,
                              void* d_out, int out_size, void* d_ws, size_t ws_size,
                              hipStream_t stream)
{
    const float* X  = (const float*)d_in[0];
    const float* Wq = (const float*)d_in[1];
    const float* Wk = (const float*)d_in[2];
    const float* Wv = (const float*)d_in[3];
    const float* Wo = (const float*)d_in[4];
    float* out = (float*)d_out;

    // ws (u16 units), liveness overlays:
    //   [0 .. 4M):   Wqkvt [3072][1024] (dead after gemm_qkv) -> AOb [4096][1024]
    //   [4M .. 16M): QKV [4096][3072] (dead after attn) -> Wot [1024][1024]
    // d_out: Xb (bf16 X, 8 MB) during xcast..gemm_qkv; final out after gemm_out.
    u16* Wt  = (u16*)d_ws;
    u16* AOb = (u16*)d_ws;
    u16* QKV = (u16*)d_ws + (size_t)4 * 1024 * 1024;
    u16* Wot = QKV;
    u16* Xb  = (u16*)out;

    xcast<<<2048, 256, 0, stream>>>(X, Xb);
    transp_cvt3<<<dim3(16, 16, 3), 256, 0, stream>>>(Wq, Wk, Wv, Wt);
    gemm_qkv<<<dim3(24, 32), 256, 0, stream>>>(Xb, Wt, QKV);  // rope fused in epilogue
    attn_mfma<<<256, 1024, 0, stream>>>(QKV, AOb);
    transp_cvt<<<dim3(16, 16), 256, 0, stream>>>(Wo, Wot);    // QKV dead now
    gemm_out<<<dim3(16, 32), 256, 0, stream>>>(AOb, Wot, out); // overwrites Xb
}

// Round 10
// 363.249 us; speedup vs baseline: 1.0054x; 1.0054x over previous
//
#include <hip/hip_runtime.h>

#define LSEQ 4096
#define DMODEL 1024
#define HTOT 16
#define NAR 8
#define DHEAD 64
#define QKVS 3072  // fused QKV row stride

typedef unsigned short u16;
typedef unsigned int u32;
typedef __attribute__((ext_vector_type(8))) short bf16x8;
typedef __attribute__((ext_vector_type(4))) short bf16x4;
typedef __attribute__((ext_vector_type(4))) float f32x4;
typedef __attribute__((ext_vector_type(4))) unsigned int u32x4;

typedef __attribute__((address_space(1))) void gvoid;
typedef __attribute__((address_space(3))) void lvoid;

__device__ __forceinline__ void cp16(const void* g, void* l) {
    // async global->LDS, 16B per lane; LDS dest = wave-uniform base + lane*16
    __builtin_amdgcn_global_load_lds((gvoid*)(void*)g, (lvoid*)l, 16, 0, 0);
}

// round-to-nearest-even fp32 -> bf16
__device__ __forceinline__ u16 f2bf(float f) {
    u32 x = __float_as_uint(f);
    return (u16)((x + 0x7fffu + ((x >> 16) & 1u)) >> 16);
}
// truncation-pack two fp32 -> packed bf16x2 (1 v_perm_b32)
__device__ __forceinline__ u32 packtr(float lo, float hi) {
    return __builtin_amdgcn_perm(__float_as_uint(hi), __float_as_uint(lo), 0x07060302u);
}

// ---------------------------------------------------------------------------
// X (fp32) -> Xb (bf16, truncated) once.
// ---------------------------------------------------------------------------
__global__ __launch_bounds__(256) void xcast(const float* __restrict__ X, u16* __restrict__ Xb)
{
    const size_t i = (size_t)(blockIdx.x * 256 + threadIdx.x) * 8;
    float4 a0 = *(const float4*)(X + i);
    float4 a1 = *(const float4*)(X + i + 4);
    uint4 pk;
    pk.x = packtr(a0.x, a0.y); pk.y = packtr(a0.z, a0.w);
    pk.z = packtr(a1.x, a1.y); pk.w = packtr(a1.z, a1.w);
    *(uint4*)(Xb + i) = pk;
}

// ---------------------------------------------------------------------------
// Fused transpose of Wq/Wk/Wv: 1024x1024 fp32 -> bf16 (D = S^T), z selects.
// ---------------------------------------------------------------------------
__global__ __launch_bounds__(256) void transp_cvt3(
    const float* __restrict__ Wq, const float* __restrict__ Wk,
    const float* __restrict__ Wv, u16* __restrict__ D)
{
    __shared__ u16 T[64][72];
    const float* S = (blockIdx.z == 0) ? Wq : ((blockIdx.z == 1) ? Wk : Wv);
    u16* Dz = D + (size_t)blockIdx.z * 1024 * 1024;
    const int tid = threadIdx.x;
    const int bx = blockIdx.x, by = blockIdx.y;
#pragma unroll
    for (int i = 0; i < 4; ++i) {
        int id = tid + i * 256;
        int fr = id >> 4, fc = id & 15;
        float4 v = *(const float4*)(S + (size_t)(by * 64 + fr) * 1024 + bx * 64 + fc * 4);
        T[fc * 4 + 0][fr] = f2bf(v.x);
        T[fc * 4 + 1][fr] = f2bf(v.y);
        T[fc * 4 + 2][fr] = f2bf(v.z);
        T[fc * 4 + 3][fr] = f2bf(v.w);
    }
    __syncthreads();
#pragma unroll
    for (int i = 0; i < 2; ++i) {
        int id = tid + i * 256;
        int c = id >> 3, g = id & 7;
        *(uint4*)(Dz + (size_t)(bx * 64 + c) * 1024 + by * 64 + g * 8) = *(const uint4*)&T[c][g * 8];
    }
}

// single-matrix version for Wo
__global__ __launch_bounds__(256) void transp_cvt(
    const float* __restrict__ S, u16* __restrict__ D)
{
    __shared__ u16 T[64][72];
    const int tid = threadIdx.x;
    const int bx = blockIdx.x, by = blockIdx.y;
#pragma unroll
    for (int i = 0; i < 4; ++i) {
        int id = tid + i * 256;
        int fr = id >> 4, fc = id & 15;
        float4 v = *(const float4*)(S + (size_t)(by * 64 + fr) * 1024 + bx * 64 + fc * 4);
        T[fc * 4 + 0][fr] = f2bf(v.x);
        T[fc * 4 + 1][fr] = f2bf(v.y);
        T[fc * 4 + 2][fr] = f2bf(v.z);
        T[fc * 4 + 3][fr] = f2bf(v.w);
    }
    __syncthreads();
#pragma unroll
    for (int i = 0; i < 2; ++i) {
        int id = tid + i * 256;
        int c = id >> 3, g = id & 7;
        *(uint4*)(D + (size_t)(bx * 64 + c) * 1024 + by * 64 + g * 8) = *(const uint4*)&T[c][g * 8];
    }
}

// ---------------------------------------------------------------------------
// QKV = Xb @ [Wq|Wk|Wv]^T(k-major) + FUSED RoPE epilogue. Pure m97 structure.
// ---------------------------------------------------------------------------
__global__ __launch_bounds__(256) void gemm_qkv(
    const u16* __restrict__ A, const u16* __restrict__ Bt, u16* __restrict__ C)
{
    __shared__ u16 As[2][128][32];
    __shared__ u16 Bs[2][128][32];
    const int tid = threadIdx.x;
    const int lane = tid & 63, w = tid >> 6;
    const int col = lane & 15, quad = lane >> 4;
    const int bm = blockIdx.y << 7, bn = blockIdx.x << 7;
    const int wm = (w & 1) << 6, wn = (w >> 1) << 6;
    const int sr = lane >> 2, sc = (lane & 3) << 3;
    const f32x4 zero = {0.f, 0.f, 0.f, 0.f};
    f32x4 acc[4][4];
#pragma unroll
    for (int i = 0; i < 4; ++i)
#pragma unroll
        for (int j = 0; j < 4; ++j) acc[i][j] = zero;

#pragma unroll
    for (int i = 0; i < 2; ++i) {
        const int r0 = w * 32 + i * 16;
        cp16(A  + (size_t)(bm + r0 + sr) * 1024 + sc, &As[0][r0][0]);
        cp16(Bt + (size_t)(bn + r0 + sr) * 1024 + sc, &Bs[0][r0][0]);
    }

    for (int kc = 0; kc < 32; ++kc) {
        const int cur = kc & 1, nxt = cur ^ 1;
        __syncthreads();
        if (kc + 1 < 32) {
            const int k1 = (kc + 1) * 32;
#pragma unroll
            for (int i = 0; i < 2; ++i) {
                const int r0 = w * 32 + i * 16;
                cp16(A  + (size_t)(bm + r0 + sr) * 1024 + k1 + sc, &As[nxt][r0][0]);
                cp16(Bt + (size_t)(bn + r0 + sr) * 1024 + k1 + sc, &Bs[nxt][r0][0]);
            }
        }
        bf16x8 af[4], bfr[4];
#pragma unroll
        for (int i = 0; i < 4; ++i) af[i] = *(const bf16x8*)&As[cur][wm + i * 16 + col][quad * 8];
#pragma unroll
        for (int j = 0; j < 4; ++j) bfr[j] = *(const bf16x8*)&Bs[cur][wn + j * 16 + col][quad * 8];
#pragma unroll
        for (int i = 0; i < 4; ++i)
#pragma unroll
            for (int j = 0; j < 4; ++j)
                acc[i][j] = __builtin_amdgcn_mfma_f32_16x16x32_bf16(af[i], bfr[j], acc[i][j], 0, 0, 0);
    }

    // fused RoPE epilogue (Q and K blocks only)
    if (blockIdx.x < 16) {
        const float scale = (blockIdx.x < 8) ? 0.18033688011112042f : 1.0f;  // Q: (1/8)*log2e
        const float inv0 = __expf((float)col * -0.2878231366242557f);         // irope = col
        const float inv1 = __expf((float)(16 + col) * -0.2878231366242557f);  // irope = 16+col
#pragma unroll
        for (int i = 0; i < 4; ++i)
#pragma unroll
            for (int r = 0; r < 4; ++r) {
                const float t = (float)(bm + wm + i * 16 + quad * 4 + r);
                float s0, c0, s1, c1;
                __sincosf(t * inv0, &s0, &c0);
                __sincosf(t * inv1, &s1, &c1);
                float a0 = acc[i][0][r], b0 = acc[i][2][r];
                acc[i][0][r] = (a0 * c0 - b0 * s0) * scale;
                acc[i][2][r] = (b0 * c0 + a0 * s0) * scale;
                float a1 = acc[i][1][r], b1 = acc[i][3][r];
                acc[i][1][r] = (a1 * c1 - b1 * s1) * scale;
                acc[i][3][r] = (b1 * c1 + a1 * s1) * scale;
            }
    }
#pragma unroll
    for (int i = 0; i < 4; ++i)
#pragma unroll
        for (int j = 0; j < 4; ++j)
#pragma unroll
            for (int r = 0; r < 4; ++r)
                C[(size_t)(bm + wm + i * 16 + quad * 4 + r) * QKVS + bn + wn + j * 16 + col] =
                    f2bf(acc[i][j][r]);
}

// ---------------------------------------------------------------------------
// out = AO @ Wot^T. 128(M)x64(N) tiles, grid 16x32 = 512 blocks (2/CU).
// ---------------------------------------------------------------------------
__global__ __launch_bounds__(256) void gemm_out(
    const u16* __restrict__ A, const u16* __restrict__ Bt, float* __restrict__ C)
{
    __shared__ u16 As[2][128][32];
    __shared__ u16 Bs[2][64][32];
    const int tid = threadIdx.x;
    const int lane = tid & 63, w = tid >> 6;
    const int col = lane & 15, quad = lane >> 4;
    const int bm = blockIdx.y << 7, bn = blockIdx.x << 6;
    const int wm = (w & 1) << 6, wn = (w >> 1) << 5;
    const int sr = lane >> 2, sc = (lane & 3) << 3;
    const f32x4 zero = {0.f, 0.f, 0.f, 0.f};
    f32x4 acc[4][2];
#pragma unroll
    for (int i = 0; i < 4; ++i)
#pragma unroll
        for (int j = 0; j < 2; ++j) acc[i][j] = zero;

    {
#pragma unroll
        for (int i = 0; i < 2; ++i) {
            const int r0 = w * 32 + i * 16;
            cp16(A + (size_t)(bm + r0 + sr) * 1024 + sc, &As[0][r0][0]);
        }
        cp16(Bt + (size_t)(bn + w * 16 + sr) * 1024 + sc, &Bs[0][w * 16][0]);
    }

    for (int kc = 0; kc < 32; ++kc) {
        const int cur = kc & 1, nxt = cur ^ 1;
        __syncthreads();
        if (kc + 1 < 32) {
            const int k1 = (kc + 1) * 32;
#pragma unroll
            for (int i = 0; i < 2; ++i) {
                const int r0 = w * 32 + i * 16;
                cp16(A + (size_t)(bm + r0 + sr) * 1024 + k1 + sc, &As[nxt][r0][0]);
            }
            cp16(Bt + (size_t)(bn + w * 16 + sr) * 1024 + k1 + sc, &Bs[nxt][w * 16][0]);
        }
        bf16x8 af[4], bfr[2];
#pragma unroll
        for (int i = 0; i < 4; ++i) af[i] = *(const bf16x8*)&As[cur][wm + i * 16 + col][quad * 8];
#pragma unroll
        for (int j = 0; j < 2; ++j) bfr[j] = *(const bf16x8*)&Bs[cur][wn + j * 16 + col][quad * 8];
#pragma unroll
        for (int i = 0; i < 4; ++i)
#pragma unroll
            for (int j = 0; j < 2; ++j)
                acc[i][j] = __builtin_amdgcn_mfma_f32_16x16x32_bf16(af[i], bfr[j], acc[i][j], 0, 0, 0);
    }
#pragma unroll
    for (int i = 0; i < 4; ++i)
#pragma unroll
        for (int j = 0; j < 2; ++j)
#pragma unroll
            for (int r = 0; r < 4; ++r)
                C[(size_t)(bm + wm + i * 16 + quad * 4 + r) * 1024 + bn + wn + j * 16 + col] =
                    acc[i][j][r];
}

// ---------------------------------------------------------------------------
// MFMA flash attention v13 — v12 with the VGPR fix:
//  * r9 failure: __launch_bounds__(1024) let the compiler target 8 waves/EU
//    (impossible: LDS 100KB = 1 block/CU) -> VGPR capped at 64 -> ~40 regs of
//    pipeline state spilled to scratch every chunk (WRITE_SIZE 333MB!).
//  * Fix: __launch_bounds__(1024, 4) = 4 waves/EU = exactly 1 block/CU ->
//    VGPR cap 128 >= the ~100 the pipeline needs. No spill.
//  * Structure unchanged from v12: block = (head, q-tile pair); 16 waves =
//    2 q-tiles x 2 KV-ranges x 4; per-KV-range Ks/Vt streams; equal-length
//    halves by q-pairing; LDS merge at the end. Chain <= 16 by construction.
// ---------------------------------------------------------------------------
__global__ __launch_bounds__(1024, 4) void attn_mfma(
    const u16* __restrict__ QKV, u16* __restrict__ AO)
{
    // per-wkv stream: [0..16384) u16 = Ks[2][128][64]; [16384..25088) = Vt[64][136]
    __shared__ u16 POOL[2][25088];
    const int bid = blockIdx.x;
    int h, pair;
    if (bid < 128) { h = 8 + (bid & 7); pair = bid >> 3; }   // diff pairs
    else { const int j = bid - 128; h = j & 7; pair = j >> 3; } // causal pairs
    const bool causal = (h < NAR);
    const int qt0 = pair * 2;
    const int L = causal ? (pair + 1) : 16;   // equal halves by construction

    const int tid = threadIdx.x;
    const int w = tid >> 6, lane = tid & 63;
    const int wkv = w >> 3;            // KV-range group (0 = merge-writer)
    const int wq = (w >> 2) & 1;       // q-tile within pair
    const int wl = w & 3;              // wave within (wkv, wq)
    const int w8 = w & 7;              // staging role within wkv-group
    const int col = lane & 15, quad = lane >> 4;
    const int qtw = qt0 + wq;
    const int qr0 = qtw * 128 + wl * 32 + col;
    const int qr1 = qr0 + 16;
    const int c0 = wkv * L, c1 = c0 + L;
    // column-permuted position of key a=2*lane (pair b=a+1 at cva+1)
    const int cva = ((lane >> 1) & 3) * 32 + (lane >> 3) * 4 + (lane & 1) * 2;

    u16 (*Ks0)[64] = (u16(*)[64]) & POOL[wkv][0];
    u16 (*Ks1)[64] = (u16(*)[64]) & POOL[wkv][8192];
    u16 (*Vt)[136] = (u16(*)[136]) & POOL[wkv][16384];
    float* LDSX = (float*)&POOL[0][0];          // [256][65] exchange (post-loop overlay)
    float* LDSL = LDSX + 256 * 65;              // [256] l exchange

    // hoisted Q B-frags (rope'd, pre-scaled by 0.125*log2e in gemm_qkv)
    bf16x8 qf[2][2];
#pragma unroll
    for (int s = 0; s < 2; ++s)
#pragma unroll
        for (int ks = 0; ks < 2; ++ks)
            qf[s][ks] = *(const bf16x8*)(QKV + (size_t)(qr0 + s * 16) * QKVS +
                                         h * DHEAD + ks * 32 + quad * 8);

    bf16x8 ones8;
#pragma unroll
    for (int i = 0; i < 8; ++i) ones8[i] = (short)0x3F80;

    const f32x4 zero = {0.f, 0.f, 0.f, 0.f};
    f32x4 O[2][5];  // [set][nd] O^T tiles (d = nd*16+quad*4+r, q = col); nd=4 = l
#pragma unroll
    for (int s = 0; s < 2; ++s)
#pragma unroll
        for (int nd = 0; nd < 5; ++nd) O[s][nd] = zero;

    const int krow = lane >> 3;
    const int kcb = (lane & 7) ^ krow;
    const u16* kbase = QKV + (size_t)krow * QKVS + 1024 + h * DHEAD + kcb * 8;
    const u16* vbase = QKV + (size_t)(lane * 2) * QKVS + 2048 + h * DHEAD + w8 * 8;

    u32x4 vA, vB;               // pending V(ch) dims [w8*8, w8*8+8) for keys 2lane, 2lane+1
    bf16x8 pf8[2][4];           // P(ch) frags: pf8[s][tp] = keys 32tp..32tp+31 (permuted)

#define KSTAGE(DST, CH)                                                                            \
    _Pragma("unroll")                                                                              \
    for (int i = 0; i < 2; ++i) {                                                                  \
        const int rb = i * 8 + w8;                                                                 \
        cp16(kbase + (size_t)((CH) * 128 + rb * 8) * QKVS, &DST[rb * 8][0]);                       \
    }

#define VLOAD(CH)                                                                                  \
    {                                                                                              \
        const u16* vp = vbase + (size_t)(CH) * 128 * QKVS;                                         \
        vA = *(u32x4*)(vp);                                                                        \
        vB = *(u32x4*)(vp + QKVS);                                                                 \
    }

#define VT_WRITE()                                                                                 \
    _Pragma("unroll")                                                                              \
    for (int j = 0; j < 4; ++j) {                                                                  \
        *(u32*)&Vt[w8 * 8 + 2 * j][cva]     = __builtin_amdgcn_perm(vB[j], vA[j], 0x05040100u);    \
        *(u32*)&Vt[w8 * 8 + 2 * j + 1][cva] = __builtin_amdgcn_perm(vB[j], vA[j], 0x07060302u);    \
    }

// PV burst over Vt at K=32: tp-outer, l-row folded in -> acc reuse distance 10.
#define PV_STEP()                                                                                  \
    {                                                                                              \
        __builtin_amdgcn_s_setprio(1);                                                             \
        _Pragma("unroll")                                                                          \
        for (int tp = 0; tp < 4; ++tp) {                                                           \
            bf16x8 vv[4];                                                                          \
            _Pragma("unroll")                                                                      \
            for (int nd = 0; nd < 4; ++nd)                                                         \
                vv[nd] = *(const bf16x8*)&Vt[nd * 16 + col][quad * 32 + tp * 8];                   \
            _Pragma("unroll")                                                                      \
            for (int nd = 0; nd < 4; ++nd) {                                                       \
                O[0][nd] = __builtin_amdgcn_mfma_f32_16x16x32_bf16(vv[nd], pf8[0][tp], O[0][nd], 0, 0, 0); \
                O[1][nd] = __builtin_amdgcn_mfma_f32_16x16x32_bf16(vv[nd], pf8[1][tp], O[1][nd], 0, 0, 0); \
            }                                                                                      \
            O[0][4] = __builtin_amdgcn_mfma_f32_16x16x32_bf16(ones8, pf8[0][tp], O[0][4], 0, 0, 0); \
            O[1][4] = __builtin_amdgcn_mfma_f32_16x16x32_bf16(ones8, pf8[1][tp], O[1][4], 0, 0, 0); \
        }                                                                                          \
        __builtin_amdgcn_s_setprio(0);                                                             \
    }

// S(CH) + exp -> pf8 from Ks buffer KB. ks-outer: st reuse distance 8.
#define S_STEP(KB, CH)                                                                             \
    {                                                                                              \
        const bool mask = causal && ((CH) == qtw);                                                 \
        _Pragma("unroll")                                                                          \
        for (int hf = 0; hf < 2; ++hf) {                                                           \
            f32x4 st[2][4];                                                                        \
            _Pragma("unroll")                                                                      \
            for (int s = 0; s < 2; ++s)                                                            \
                _Pragma("unroll")                                                                  \
                for (int jj = 0; jj < 4; ++jj) st[s][jj] = zero;                                   \
            __builtin_amdgcn_s_setprio(1);                                                         \
            _Pragma("unroll")                                                                      \
            for (int ks = 0; ks < 2; ++ks)                                                         \
                _Pragma("unroll")                                                                  \
                for (int jj = 0; jj < 4; ++jj) {                                                   \
                    bf16x8 kf = *(const bf16x8*)&KB[(hf * 4 + jj) * 16 + col]                      \
                                                  [((ks * 4 + quad) ^ (col & 7)) * 8];             \
                    st[0][jj] = __builtin_amdgcn_mfma_f32_16x16x32_bf16(kf, qf[0][ks], st[0][jj], 0, 0, 0); \
                    st[1][jj] = __builtin_amdgcn_mfma_f32_16x16x32_bf16(kf, qf[1][ks], st[1][jj], 0, 0, 0); \
                }                                                                                  \
            __builtin_amdgcn_s_setprio(0);                                                         \
            if (mask) {                                                                            \
                _Pragma("unroll")                                                                  \
                for (int jj = 0; jj < 4; ++jj) {                                                   \
                    const int kk = (CH) * 128 + (hf * 4 + jj) * 16 + quad * 4;                     \
                    _Pragma("unroll")                                                              \
                    for (int r = 0; r < 4; ++r) {                                                  \
                        if (kk + r > qr0) st[0][jj][r] = -1e30f;                                   \
                        if (kk + r > qr1) st[1][jj][r] = -1e30f;                                   \
                    }                                                                              \
                }                                                                                  \
            }                                                                                      \
            _Pragma("unroll")                                                                      \
            for (int s = 0; s < 2; ++s)                                                            \
                _Pragma("unroll")                                                                  \
                for (int jj = 0; jj < 4; ++jj) {                                                   \
                    u32 plo = packtr(__builtin_amdgcn_exp2f(st[s][jj][0]),                         \
                                     __builtin_amdgcn_exp2f(st[s][jj][1]));                        \
                    u32 phi = packtr(__builtin_amdgcn_exp2f(st[s][jj][2]),                         \
                                     __builtin_amdgcn_exp2f(st[s][jj][3]));                        \
                    u32* p = (u32*)&pf8[s][0] + (hf * 4 + jj) * 2;                                 \
                    p[0] = plo; p[1] = phi;                                                        \
                }                                                                                  \
        }                                                                                          \
    }

    // ---- prologue: stage chunk c0 ----
    KSTAGE(Ks0, c0);
    VLOAD(c0);
    __syncthreads();  // both streams' K(c0) in LDS, V(c0) in regs
    VT_WRITE();       // Vt <- V(c0); visible after next barrier
    if (L > 1) { KSTAGE(Ks1, c0 + 1); }
    if (!causal || c0 <= qtw) { S_STEP(Ks0, c0); }   // pf8 = P(c0)

    // ---- main loop (uniform L iterations across all 16 waves) ----
    for (int it = 1; it < L; ++it) {
        const int ch = c0 + it;
        u16 (*KB)[64] = (it & 1) ? Ks1 : Ks0;
        u16 (*KN)[64] = (it & 1) ? Ks0 : Ks1;
        __syncthreads();  // barrier_a: K(ch) drained; Vt = V(ch-1) visible
        if (it + 1 < L) { KSTAGE(KN, ch + 1); }
        VLOAD(ch);
        if (!causal || (ch - 1) <= qtw) { PV_STEP(); }   // P(ch-1) x V(ch-1)
        if (!causal || ch <= qtw) { S_STEP(KB, ch); }    // pf8 = P(ch)
        __syncthreads();  // barrier_b: all PV reads of Vt done
        VT_WRITE();       // Vt <- V(ch)
    }

    // ---- tail: PV(c1-1) ----
    __syncthreads();  // Vt = V(c1-1) visible
    if (!causal || (c1 - 1) <= qtw) { PV_STEP(); }

    // ---- intra-block merge: wkv1 -> LDS, wkv0 adds + writes AO ----
    __syncthreads();  // all K/V LDS dead; overlay exchange buffer
    const int ql = wq * 128 + wl * 32 + col;
    if (wkv == 1) {
#pragma unroll
        for (int s = 0; s < 2; ++s) {
            const int q = ql + s * 16;
#pragma unroll
            for (int nd = 0; nd < 4; ++nd)
                *(f32x4*)&LDSX[(size_t)q * 65 + nd * 16 + quad * 4] = O[s][nd];
            if (quad == 0) LDSL[q] = O[s][4][0];
        }
    }
    __syncthreads();
    if (wkv == 0) {
#pragma unroll
        for (int s = 0; s < 2; ++s) {
            const int q = ql + s * 16;
            const float l = O[s][4][0] + LDSL[q];
            const float inv = 1.f / l;
            const int qrow = qr0 + s * 16;
#pragma unroll
            for (int nd = 0; nd < 4; ++nd) {
                f32x4 pv = *(const f32x4*)&LDSX[(size_t)q * 65 + nd * 16 + quad * 4];
                ushort4 ov;
                ov.x = f2bf((O[s][nd][0] + pv[0]) * inv);
                ov.y = f2bf((O[s][nd][1] + pv[1]) * inv);
                ov.z = f2bf((O[s][nd][2] + pv[2]) * inv);
                ov.w = f2bf((O[s][nd][3] + pv[3]) * inv);
                *(ushort4*)(AO + (size_t)qrow * 1024 + h * DHEAD + nd * 16 + quad * 4) = ov;
            }
        }
    }
#undef KSTAGE
#undef VLOAD
#undef VT_WRITE
#undef PV_STEP
#undef S_STEP
}

// ---------------------------------------------------------------------------
extern "C" void kernel_launch(void* const* d_in, const int* in_sizes, int n_in,
                              void* d_out, int out_size, void* d_ws, size_t ws_size,
                              hipStream_t stream)
{
    const float* X  = (const float*)d_in[0];
    const float* Wq = (const float*)d_in[1];
    const float* Wk = (const float*)d_in[2];
    const float* Wv = (const float*)d_in[3];
    const float* Wo = (const float*)d_in[4];
    float* out = (float*)d_out;

    // ws (u16 units), liveness overlays:
    //   [0 .. 4M):   Wqkvt [3072][1024] (dead after gemm_qkv) -> AOb [4096][1024]
    //   [4M .. 16M): QKV [4096][3072] (dead after attn) -> Wot [1024][1024]
    // d_out: Xb (bf16 X, 8 MB) during xcast..gemm_qkv; final out after gemm_out.
    u16* Wt  = (u16*)d_ws;
    u16* AOb = (u16*)d_ws;
    u16* QKV = (u16*)d_ws + (size_t)4 * 1024 * 1024;
    u16* Wot = QKV;
    u16* Xb  = (u16*)out;

    xcast<<<2048, 256, 0, stream>>>(X, Xb);
    transp_cvt3<<<dim3(16, 16, 3), 256, 0, stream>>>(Wq, Wk, Wv, Wt);
    gemm_qkv<<<dim3(24, 32), 256, 0, stream>>>(Xb, Wt, QKV);  // rope fused in epilogue
    attn_mfma<<<256, 1024, 0, stream>>>(QKV, AOb);
    transp_cvt<<<dim3(16, 16), 256, 0, stream>>>(Wo, Wot);    // QKV dead now
    gemm_out<<<dim3(16, 32), 256, 0, stream>>>(AOb, Wot, out); // overwrites Xb
}

// Round 11
// 362.987 us; speedup vs baseline: 1.0061x; 1.0007x over previous
//
#include <hip/hip_runtime.h>

#define LSEQ 4096
#define DMODEL 1024
#define HTOT 16
#define NAR 8
#define DHEAD 64
#define QKVS 3072  // fused QKV row stride

typedef unsigned short u16;
typedef unsigned int u32;
typedef __attribute__((ext_vector_type(8))) short bf16x8;
typedef __attribute__((ext_vector_type(4))) short bf16x4;
typedef __attribute__((ext_vector_type(4))) float f32x4;
typedef __attribute__((ext_vector_type(4))) unsigned int u32x4;

typedef __attribute__((address_space(1))) void gvoid;
typedef __attribute__((address_space(3))) void lvoid;

__device__ __forceinline__ void cp16(const void* g, void* l) {
    // async global->LDS, 16B per lane; LDS dest = wave-uniform base + lane*16
    __builtin_amdgcn_global_load_lds((gvoid*)(void*)g, (lvoid*)l, 16, 0, 0);
}

// round-to-nearest-even fp32 -> bf16
__device__ __forceinline__ u16 f2bf(float f) {
    u32 x = __float_as_uint(f);
    return (u16)((x + 0x7fffu + ((x >> 16) & 1u)) >> 16);
}
// truncation-pack two fp32 -> packed bf16x2 (1 v_perm_b32)
__device__ __forceinline__ u32 packtr(float lo, float hi) {
    return __builtin_amdgcn_perm(__float_as_uint(hi), __float_as_uint(lo), 0x07060302u);
}

// ---------------------------------------------------------------------------
// X (fp32) -> Xb (bf16, truncated) once.
// ---------------------------------------------------------------------------
__global__ __launch_bounds__(256) void xcast(const float* __restrict__ X, u16* __restrict__ Xb)
{
    const size_t i = (size_t)(blockIdx.x * 256 + threadIdx.x) * 8;
    float4 a0 = *(const float4*)(X + i);
    float4 a1 = *(const float4*)(X + i + 4);
    uint4 pk;
    pk.x = packtr(a0.x, a0.y); pk.y = packtr(a0.z, a0.w);
    pk.z = packtr(a1.x, a1.y); pk.w = packtr(a1.z, a1.w);
    *(uint4*)(Xb + i) = pk;
}

// ---------------------------------------------------------------------------
// Fused transpose of Wq/Wk/Wv: 1024x1024 fp32 -> bf16 (D = S^T), z selects.
// ---------------------------------------------------------------------------
__global__ __launch_bounds__(256) void transp_cvt3(
    const float* __restrict__ Wq, const float* __restrict__ Wk,
    const float* __restrict__ Wv, u16* __restrict__ D)
{
    __shared__ u16 T[64][72];
    const float* S = (blockIdx.z == 0) ? Wq : ((blockIdx.z == 1) ? Wk : Wv);
    u16* Dz = D + (size_t)blockIdx.z * 1024 * 1024;
    const int tid = threadIdx.x;
    const int bx = blockIdx.x, by = blockIdx.y;
#pragma unroll
    for (int i = 0; i < 4; ++i) {
        int id = tid + i * 256;
        int fr = id >> 4, fc = id & 15;
        float4 v = *(const float4*)(S + (size_t)(by * 64 + fr) * 1024 + bx * 64 + fc * 4);
        T[fc * 4 + 0][fr] = f2bf(v.x);
        T[fc * 4 + 1][fr] = f2bf(v.y);
        T[fc * 4 + 2][fr] = f2bf(v.z);
        T[fc * 4 + 3][fr] = f2bf(v.w);
    }
    __syncthreads();
#pragma unroll
    for (int i = 0; i < 2; ++i) {
        int id = tid + i * 256;
        int c = id >> 3, g = id & 7;
        *(uint4*)(Dz + (size_t)(bx * 64 + c) * 1024 + by * 64 + g * 8) = *(const uint4*)&T[c][g * 8];
    }
}

// single-matrix version for Wo
__global__ __launch_bounds__(256) void transp_cvt(
    const float* __restrict__ S, u16* __restrict__ D)
{
    __shared__ u16 T[64][72];
    const int tid = threadIdx.x;
    const int bx = blockIdx.x, by = blockIdx.y;
#pragma unroll
    for (int i = 0; i < 4; ++i) {
        int id = tid + i * 256;
        int fr = id >> 4, fc = id & 15;
        float4 v = *(const float4*)(S + (size_t)(by * 64 + fr) * 1024 + bx * 64 + fc * 4);
        T[fc * 4 + 0][fr] = f2bf(v.x);
        T[fc * 4 + 1][fr] = f2bf(v.y);
        T[fc * 4 + 2][fr] = f2bf(v.z);
        T[fc * 4 + 3][fr] = f2bf(v.w);
    }
    __syncthreads();
#pragma unroll
    for (int i = 0; i < 2; ++i) {
        int id = tid + i * 256;
        int c = id >> 3, g = id & 7;
        *(uint4*)(D + (size_t)(bx * 64 + c) * 1024 + by * 64 + g * 8) = *(const uint4*)&T[c][g * 8];
    }
}

// ---------------------------------------------------------------------------
// QKV = Xb @ [Wq|Wk|Wv]^T(k-major) + FUSED RoPE epilogue. Pure m97 structure.
// ---------------------------------------------------------------------------
__global__ __launch_bounds__(256) void gemm_qkv(
    const u16* __restrict__ A, const u16* __restrict__ Bt, u16* __restrict__ C)
{
    __shared__ u16 As[2][128][32];
    __shared__ u16 Bs[2][128][32];
    const int tid = threadIdx.x;
    const int lane = tid & 63, w = tid >> 6;
    const int col = lane & 15, quad = lane >> 4;
    const int bm = blockIdx.y << 7, bn = blockIdx.x << 7;
    const int wm = (w & 1) << 6, wn = (w >> 1) << 6;
    const int sr = lane >> 2, sc = (lane & 3) << 3;
    const f32x4 zero = {0.f, 0.f, 0.f, 0.f};
    f32x4 acc[4][4];
#pragma unroll
    for (int i = 0; i < 4; ++i)
#pragma unroll
        for (int j = 0; j < 4; ++j) acc[i][j] = zero;

#pragma unroll
    for (int i = 0; i < 2; ++i) {
        const int r0 = w * 32 + i * 16;
        cp16(A  + (size_t)(bm + r0 + sr) * 1024 + sc, &As[0][r0][0]);
        cp16(Bt + (size_t)(bn + r0 + sr) * 1024 + sc, &Bs[0][r0][0]);
    }

    for (int kc = 0; kc < 32; ++kc) {
        const int cur = kc & 1, nxt = cur ^ 1;
        __syncthreads();
        if (kc + 1 < 32) {
            const int k1 = (kc + 1) * 32;
#pragma unroll
            for (int i = 0; i < 2; ++i) {
                const int r0 = w * 32 + i * 16;
                cp16(A  + (size_t)(bm + r0 + sr) * 1024 + k1 + sc, &As[nxt][r0][0]);
                cp16(Bt + (size_t)(bn + r0 + sr) * 1024 + k1 + sc, &Bs[nxt][r0][0]);
            }
        }
        bf16x8 af[4], bfr[4];
#pragma unroll
        for (int i = 0; i < 4; ++i) af[i] = *(const bf16x8*)&As[cur][wm + i * 16 + col][quad * 8];
#pragma unroll
        for (int j = 0; j < 4; ++j) bfr[j] = *(const bf16x8*)&Bs[cur][wn + j * 16 + col][quad * 8];
#pragma unroll
        for (int i = 0; i < 4; ++i)
#pragma unroll
            for (int j = 0; j < 4; ++j)
                acc[i][j] = __builtin_amdgcn_mfma_f32_16x16x32_bf16(af[i], bfr[j], acc[i][j], 0, 0, 0);
    }

    // fused RoPE epilogue (Q and K blocks only)
    if (blockIdx.x < 16) {
        const float scale = (blockIdx.x < 8) ? 0.18033688011112042f : 1.0f;  // Q: (1/8)*log2e
        const float inv0 = __expf((float)col * -0.2878231366242557f);         // irope = col
        const float inv1 = __expf((float)(16 + col) * -0.2878231366242557f);  // irope = 16+col
#pragma unroll
        for (int i = 0; i < 4; ++i)
#pragma unroll
            for (int r = 0; r < 4; ++r) {
                const float t = (float)(bm + wm + i * 16 + quad * 4 + r);
                float s0, c0, s1, c1;
                __sincosf(t * inv0, &s0, &c0);
                __sincosf(t * inv1, &s1, &c1);
                float a0 = acc[i][0][r], b0 = acc[i][2][r];
                acc[i][0][r] = (a0 * c0 - b0 * s0) * scale;
                acc[i][2][r] = (b0 * c0 + a0 * s0) * scale;
                float a1 = acc[i][1][r], b1 = acc[i][3][r];
                acc[i][1][r] = (a1 * c1 - b1 * s1) * scale;
                acc[i][3][r] = (b1 * c1 + a1 * s1) * scale;
            }
    }
#pragma unroll
    for (int i = 0; i < 4; ++i)
#pragma unroll
        for (int j = 0; j < 4; ++j)
#pragma unroll
            for (int r = 0; r < 4; ++r)
                C[(size_t)(bm + wm + i * 16 + quad * 4 + r) * QKVS + bn + wn + j * 16 + col] =
                    f2bf(acc[i][j][r]);
}

// ---------------------------------------------------------------------------
// out = AO @ Wot^T. 128(M)x64(N) tiles, grid 16x32 = 512 blocks (2/CU).
// ---------------------------------------------------------------------------
__global__ __launch_bounds__(256) void gemm_out(
    const u16* __restrict__ A, const u16* __restrict__ Bt, float* __restrict__ C)
{
    __shared__ u16 As[2][128][32];
    __shared__ u16 Bs[2][64][32];
    const int tid = threadIdx.x;
    const int lane = tid & 63, w = tid >> 6;
    const int col = lane & 15, quad = lane >> 4;
    const int bm = blockIdx.y << 7, bn = blockIdx.x << 6;
    const int wm = (w & 1) << 6, wn = (w >> 1) << 5;
    const int sr = lane >> 2, sc = (lane & 3) << 3;
    const f32x4 zero = {0.f, 0.f, 0.f, 0.f};
    f32x4 acc[4][2];
#pragma unroll
    for (int i = 0; i < 4; ++i)
#pragma unroll
        for (int j = 0; j < 2; ++j) acc[i][j] = zero;

    {
#pragma unroll
        for (int i = 0; i < 2; ++i) {
            const int r0 = w * 32 + i * 16;
            cp16(A + (size_t)(bm + r0 + sr) * 1024 + sc, &As[0][r0][0]);
        }
        cp16(Bt + (size_t)(bn + w * 16 + sr) * 1024 + sc, &Bs[0][w * 16][0]);
    }

    for (int kc = 0; kc < 32; ++kc) {
        const int cur = kc & 1, nxt = cur ^ 1;
        __syncthreads();
        if (kc + 1 < 32) {
            const int k1 = (kc + 1) * 32;
#pragma unroll
            for (int i = 0; i < 2; ++i) {
                const int r0 = w * 32 + i * 16;
                cp16(A + (size_t)(bm + r0 + sr) * 1024 + k1 + sc, &As[nxt][r0][0]);
            }
            cp16(Bt + (size_t)(bn + w * 16 + sr) * 1024 + k1 + sc, &Bs[nxt][w * 16][0]);
        }
        bf16x8 af[4], bfr[2];
#pragma unroll
        for (int i = 0; i < 4; ++i) af[i] = *(const bf16x8*)&As[cur][wm + i * 16 + col][quad * 8];
#pragma unroll
        for (int j = 0; j < 2; ++j) bfr[j] = *(const bf16x8*)&Bs[cur][wn + j * 16 + col][quad * 8];
#pragma unroll
        for (int i = 0; i < 4; ++i)
#pragma unroll
            for (int j = 0; j < 2; ++j)
                acc[i][j] = __builtin_amdgcn_mfma_f32_16x16x32_bf16(af[i], bfr[j], acc[i][j], 0, 0, 0);
    }
#pragma unroll
    for (int i = 0; i < 4; ++i)
#pragma unroll
        for (int j = 0; j < 2; ++j)
#pragma unroll
            for (int r = 0; r < 4; ++r)
                C[(size_t)(bm + wm + i * 16 + quad * 4 + r) * 1024 + bn + wn + j * 16 + col] =
                    acc[i][j][r];
}

// ---------------------------------------------------------------------------
// MFMA flash attention v14 — v13 with the VGPR budget forced via the direct
// LLVM attribute:
//  * r9/r10 evidence: __launch_bounds__(1024[,4]) left the allocator at a
//    64-VGPR budget (8 waves/EU target) -> ~40 regs spilled per chunk
//    (WRITE_SIZE 333MB, FETCH 132MB, dur 209us). The launch_bounds path does
//    not raise the budget on 1024-thread kernels.
//  * Fix: __attribute__((amdgpu_waves_per_eu(4, 4))) — exact occupancy range,
//    budget = 512-VGPR pool / 4 = 128 >= the ~100-120 the pipeline needs
//    (the identical per-wave body fit in 100 VGPRs in the 256-thread r5/r7
//    kernels). LDS (100KB) already restricts to 1 block/CU = 4 waves/EU, so
//    (4,4) costs nothing.
//  * Structure unchanged from v12/v13: block = (head, q-tile pair); 16 waves
//    = 2 q-tiles x 2 KV-ranges x 4; per-KV-range Ks/Vt streams; equal-length
//    halves by q-pairing; LDS merge at the end. Chain <= 16 by construction.
//    Each SIMD hosts 4 waves from 4 different (wq,wkv) units -> independent
//    work overlaps the per-chunk latency between barriers (the same
//    mechanism that made r3/r5 co-resident blocks overlap fully).
// ---------------------------------------------------------------------------
__attribute__((amdgpu_waves_per_eu(4, 4)))
__global__ __launch_bounds__(1024) void attn_mfma(
    const u16* __restrict__ QKV, u16* __restrict__ AO)
{
    // per-wkv stream: [0..16384) u16 = Ks[2][128][64]; [16384..25088) = Vt[64][136]
    __shared__ u16 POOL[2][25088];
    const int bid = blockIdx.x;
    int h, pair;
    if (bid < 128) { h = 8 + (bid & 7); pair = bid >> 3; }   // diff pairs
    else { const int j = bid - 128; h = j & 7; pair = j >> 3; } // causal pairs
    const bool causal = (h < NAR);
    const int qt0 = pair * 2;
    const int L = causal ? (pair + 1) : 16;   // equal halves by construction

    const int tid = threadIdx.x;
    const int w = tid >> 6, lane = tid & 63;
    const int wkv = w >> 3;            // KV-range group (0 = merge-writer)
    const int wq = (w >> 2) & 1;       // q-tile within pair
    const int wl = w & 3;              // wave within (wkv, wq)
    const int w8 = w & 7;              // staging role within wkv-group
    const int col = lane & 15, quad = lane >> 4;
    const int qtw = qt0 + wq;
    const int qr0 = qtw * 128 + wl * 32 + col;
    const int qr1 = qr0 + 16;
    const int c0 = wkv * L, c1 = c0 + L;
    // column-permuted position of key a=2*lane (pair b=a+1 at cva+1)
    const int cva = ((lane >> 1) & 3) * 32 + (lane >> 3) * 4 + (lane & 1) * 2;

    u16 (*Ks0)[64] = (u16(*)[64]) & POOL[wkv][0];
    u16 (*Ks1)[64] = (u16(*)[64]) & POOL[wkv][8192];
    u16 (*Vt)[136] = (u16(*)[136]) & POOL[wkv][16384];
    float* LDSX = (float*)&POOL[0][0];          // [256][65] exchange (post-loop overlay)
    float* LDSL = LDSX + 256 * 65;              // [256] l exchange

    // hoisted Q B-frags (rope'd, pre-scaled by 0.125*log2e in gemm_qkv)
    bf16x8 qf[2][2];
#pragma unroll
    for (int s = 0; s < 2; ++s)
#pragma unroll
        for (int ks = 0; ks < 2; ++ks)
            qf[s][ks] = *(const bf16x8*)(QKV + (size_t)(qr0 + s * 16) * QKVS +
                                         h * DHEAD + ks * 32 + quad * 8);

    bf16x8 ones8;
#pragma unroll
    for (int i = 0; i < 8; ++i) ones8[i] = (short)0x3F80;

    const f32x4 zero = {0.f, 0.f, 0.f, 0.f};
    f32x4 O[2][5];  // [set][nd] O^T tiles (d = nd*16+quad*4+r, q = col); nd=4 = l
#pragma unroll
    for (int s = 0; s < 2; ++s)
#pragma unroll
        for (int nd = 0; nd < 5; ++nd) O[s][nd] = zero;

    const int krow = lane >> 3;
    const int kcb = (lane & 7) ^ krow;
    const u16* kbase = QKV + (size_t)krow * QKVS + 1024 + h * DHEAD + kcb * 8;
    const u16* vbase = QKV + (size_t)(lane * 2) * QKVS + 2048 + h * DHEAD + w8 * 8;

    u32x4 vA, vB;               // pending V(ch) dims [w8*8, w8*8+8) for keys 2lane, 2lane+1
    bf16x8 pf8[2][4];           // P(ch) frags: pf8[s][tp] = keys 32tp..32tp+31 (permuted)

#define KSTAGE(DST, CH)                                                                            \
    _Pragma("unroll")                                                                              \
    for (int i = 0; i < 2; ++i) {                                                                  \
        const int rb = i * 8 + w8;                                                                 \
        cp16(kbase + (size_t)((CH) * 128 + rb * 8) * QKVS, &DST[rb * 8][0]);                       \
    }

#define VLOAD(CH)                                                                                  \
    {                                                                                              \
        const u16* vp = vbase + (size_t)(CH) * 128 * QKVS;                                         \
        vA = *(u32x4*)(vp);                                                                        \
        vB = *(u32x4*)(vp + QKVS);                                                                 \
    }

#define VT_WRITE()                                                                                 \
    _Pragma("unroll")                                                                              \
    for (int j = 0; j < 4; ++j) {                                                                  \
        *(u32*)&Vt[w8 * 8 + 2 * j][cva]     = __builtin_amdgcn_perm(vB[j], vA[j], 0x05040100u);    \
        *(u32*)&Vt[w8 * 8 + 2 * j + 1][cva] = __builtin_amdgcn_perm(vB[j], vA[j], 0x07060302u);    \
    }

// PV burst over Vt at K=32: tp-outer, l-row folded in -> acc reuse distance 10.
#define PV_STEP()                                                                                  \
    {                                                                                              \
        __builtin_amdgcn_s_setprio(1);                                                             \
        _Pragma("unroll")                                                                          \
        for (int tp = 0; tp < 4; ++tp) {                                                           \
            bf16x8 vv[4];                                                                          \
            _Pragma("unroll")                                                                      \
            for (int nd = 0; nd < 4; ++nd)                                                         \
                vv[nd] = *(const bf16x8*)&Vt[nd * 16 + col][quad * 32 + tp * 8];                   \
            _Pragma("unroll")                                                                      \
            for (int nd = 0; nd < 4; ++nd) {                                                       \
                O[0][nd] = __builtin_amdgcn_mfma_f32_16x16x32_bf16(vv[nd], pf8[0][tp], O[0][nd], 0, 0, 0); \
                O[1][nd] = __builtin_amdgcn_mfma_f32_16x16x32_bf16(vv[nd], pf8[1][tp], O[1][nd], 0, 0, 0); \
            }                                                                                      \
            O[0][4] = __builtin_amdgcn_mfma_f32_16x16x32_bf16(ones8, pf8[0][tp], O[0][4], 0, 0, 0); \
            O[1][4] = __builtin_amdgcn_mfma_f32_16x16x32_bf16(ones8, pf8[1][tp], O[1][4], 0, 0, 0); \
        }                                                                                          \
        __builtin_amdgcn_s_setprio(0);                                                             \
    }

// S(CH) + exp -> pf8 from Ks buffer KB. ks-outer: st reuse distance 8.
#define S_STEP(KB, CH)                                                                             \
    {                                                                                              \
        const bool mask = causal && ((CH) == qtw);                                                 \
        _Pragma("unroll")                                                                          \
        for (int hf = 0; hf < 2; ++hf) {                                                           \
            f32x4 st[2][4];                                                                        \
            _Pragma("unroll")                                                                      \
            for (int s = 0; s < 2; ++s)                                                            \
                _Pragma("unroll")                                                                  \
                for (int jj = 0; jj < 4; ++jj) st[s][jj] = zero;                                   \
            __builtin_amdgcn_s_setprio(1);                                                         \
            _Pragma("unroll")                                                                      \
            for (int ks = 0; ks < 2; ++ks)                                                         \
                _Pragma("unroll")                                                                  \
                for (int jj = 0; jj < 4; ++jj) {                                                   \
                    bf16x8 kf = *(const bf16x8*)&KB[(hf * 4 + jj) * 16 + col]                      \
                                                  [((ks * 4 + quad) ^ (col & 7)) * 8];             \
                    st[0][jj] = __builtin_amdgcn_mfma_f32_16x16x32_bf16(kf, qf[0][ks], st[0][jj], 0, 0, 0); \
                    st[1][jj] = __builtin_amdgcn_mfma_f32_16x16x32_bf16(kf, qf[1][ks], st[1][jj], 0, 0, 0); \
                }                                                                                  \
            __builtin_amdgcn_s_setprio(0);                                                         \
            if (mask) {                                                                            \
                _Pragma("unroll")                                                                  \
                for (int jj = 0; jj < 4; ++jj) {                                                   \
                    const int kk = (CH) * 128 + (hf * 4 + jj) * 16 + quad * 4;                     \
                    _Pragma("unroll")                                                              \
                    for (int r = 0; r < 4; ++r) {                                                  \
                        if (kk + r > qr0) st[0][jj][r] = -1e30f;                                   \
                        if (kk + r > qr1) st[1][jj][r] = -1e30f;                                   \
                    }                                                                              \
                }                                                                                  \
            }                                                                                      \
            _Pragma("unroll")                                                                      \
            for (int s = 0; s < 2; ++s)                                                            \
                _Pragma("unroll")                                                                  \
                for (int jj = 0; jj < 4; ++jj) {                                                   \
                    u32 plo = packtr(__builtin_amdgcn_exp2f(st[s][jj][0]),                         \
                                     __builtin_amdgcn_exp2f(st[s][jj][1]));                        \
                    u32 phi = packtr(__builtin_amdgcn_exp2f(st[s][jj][2]),                         \
                                     __builtin_amdgcn_exp2f(st[s][jj][3]));                        \
                    u32* p = (u32*)&pf8[s][0] + (hf * 4 + jj) * 2;                                 \
                    p[0] = plo; p[1] = phi;                                                        \
                }                                                                                  \
        }                                                                                          \
    }

    // ---- prologue: stage chunk c0 ----
    KSTAGE(Ks0, c0);
    VLOAD(c0);
    __syncthreads();  // both streams' K(c0) in LDS, V(c0) in regs
    VT_WRITE();       // Vt <- V(c0); visible after next barrier
    if (L > 1) { KSTAGE(Ks1, c0 + 1); }
    if (!causal || c0 <= qtw) { S_STEP(Ks0, c0); }   // pf8 = P(c0)

    // ---- main loop (uniform L iterations across all 16 waves) ----
    for (int it = 1; it < L; ++it) {
        const int ch = c0 + it;
        u16 (*KB)[64] = (it & 1) ? Ks1 : Ks0;
        u16 (*KN)[64] = (it & 1) ? Ks0 : Ks1;
        __syncthreads();  // barrier_a: K(ch) drained; Vt = V(ch-1) visible
        if (it + 1 < L) { KSTAGE(KN, ch + 1); }
        VLOAD(ch);
        if (!causal || (ch - 1) <= qtw) { PV_STEP(); }   // P(ch-1) x V(ch-1)
        if (!causal || ch <= qtw) { S_STEP(KB, ch); }    // pf8 = P(ch)
        __syncthreads();  // barrier_b: all PV reads of Vt done
        VT_WRITE();       // Vt <- V(ch)
    }

    // ---- tail: PV(c1-1) ----
    __syncthreads();  // Vt = V(c1-1) visible
    if (!causal || (c1 - 1) <= qtw) { PV_STEP(); }

    // ---- intra-block merge: wkv1 -> LDS, wkv0 adds + writes AO ----
    __syncthreads();  // all K/V LDS dead; overlay exchange buffer
    const int ql = wq * 128 + wl * 32 + col;
    if (wkv == 1) {
#pragma unroll
        for (int s = 0; s < 2; ++s) {
            const int q = ql + s * 16;
#pragma unroll
            for (int nd = 0; nd < 4; ++nd)
                *(f32x4*)&LDSX[(size_t)q * 65 + nd * 16 + quad * 4] = O[s][nd];
            if (quad == 0) LDSL[q] = O[s][4][0];
        }
    }
    __syncthreads();
    if (wkv == 0) {
#pragma unroll
        for (int s = 0; s < 2; ++s) {
            const int q = ql + s * 16;
            const float l = O[s][4][0] + LDSL[q];
            const float inv = 1.f / l;
            const int qrow = qr0 + s * 16;
#pragma unroll
            for (int nd = 0; nd < 4; ++nd) {
                f32x4 pv = *(const f32x4*)&LDSX[(size_t)q * 65 + nd * 16 + quad * 4];
                ushort4 ov;
                ov.x = f2bf((O[s][nd][0] + pv[0]) * inv);
                ov.y = f2bf((O[s][nd][1] + pv[1]) * inv);
                ov.z = f2bf((O[s][nd][2] + pv[2]) * inv);
                ov.w = f2bf((O[s][nd][3] + pv[3]) * inv);
                *(ushort4*)(AO + (size_t)qrow * 1024 + h * DHEAD + nd * 16 + quad * 4) = ov;
            }
        }
    }
#undef KSTAGE
#undef VLOAD
#undef VT_WRITE
#undef PV_STEP
#undef S_STEP
}

// ---------------------------------------------------------------------------
extern "C" void kernel_launch(void* const* d_in, const int* in_sizes, int n_in,
                              void* d_out, int out_size, void* d_ws, size_t ws_size,
                              hipStream_t stream)
{
    const float* X  = (const float*)d_in[0];
    const float* Wq = (const float*)d_in[1];
    const float* Wk = (const float*)d_in[2];
    const float* Wv = (const float*)d_in[3];
    const float* Wo = (const float*)d_in[4];
    float* out = (float*)d_out;

    // ws (u16 units), liveness overlays:
    //   [0 .. 4M):   Wqkvt [3072][1024] (dead after gemm_qkv) -> AOb [4096][1024]
    //   [4M .. 16M): QKV [4096][3072] (dead after attn) -> Wot [1024][1024]
    // d_out: Xb (bf16 X, 8 MB) during xcast..gemm_qkv; final out after gemm_out.
    u16* Wt  = (u16*)d_ws;
    u16* AOb = (u16*)d_ws;
    u16* QKV = (u16*)d_ws + (size_t)4 * 1024 * 1024;
    u16* Wot = QKV;
    u16* Xb  = (u16*)out;

    xcast<<<2048, 256, 0, stream>>>(X, Xb);
    transp_cvt3<<<dim3(16, 16, 3), 256, 0, stream>>>(Wq, Wk, Wv, Wt);
    gemm_qkv<<<dim3(24, 32), 256, 0, stream>>>(Xb, Wt, QKV);  // rope fused in epilogue
    attn_mfma<<<256, 1024, 0, stream>>>(QKV, AOb);
    transp_cvt<<<dim3(16, 16), 256, 0, stream>>>(Wo, Wot);    // QKV dead now
    gemm_out<<<dim3(16, 32), 256, 0, stream>>>(AOb, Wot, out); // overwrites Xb
}

// Round 13
// 240.495 us; speedup vs baseline: 1.5186x; 1.5093x over previous
//
#include <hip/hip_runtime.h>

#define LSEQ 4096
#define DMODEL 1024
#define HTOT 16
#define NAR 8
#define DHEAD 64
#define QKVS 3072  // fused QKV row stride

typedef unsigned short u16;
typedef unsigned int u32;
typedef __attribute__((ext_vector_type(8))) short bf16x8;
typedef __attribute__((ext_vector_type(4))) short bf16x4;
typedef __attribute__((ext_vector_type(4))) float f32x4;
typedef __attribute__((ext_vector_type(4))) unsigned int u32x4;

typedef __attribute__((address_space(1))) void gvoid;
typedef __attribute__((address_space(3))) void lvoid;

__device__ __forceinline__ void cp16(const void* g, void* l) {
    // async global->LDS, 16B per lane; LDS dest = wave-uniform base + lane*16
    __builtin_amdgcn_global_load_lds((gvoid*)(void*)g, (lvoid*)l, 16, 0, 0);
}

// round-to-nearest-even fp32 -> bf16
__device__ __forceinline__ u16 f2bf(float f) {
    u32 x = __float_as_uint(f);
    return (u16)((x + 0x7fffu + ((x >> 16) & 1u)) >> 16);
}
// truncation-pack two fp32 -> packed bf16x2 (1 v_perm_b32)
__device__ __forceinline__ u32 packtr(float lo, float hi) {
    return __builtin_amdgcn_perm(__float_as_uint(hi), __float_as_uint(lo), 0x07060302u);
}

// ---------------------------------------------------------------------------
// X (fp32) -> Xb (bf16, truncated) once, so gemm_qkv needs no per-K-step
// VALU repack. Bit-identical to the old in-loop packtr path.
// ---------------------------------------------------------------------------
__global__ __launch_bounds__(256) void xcast(const float* __restrict__ X, u16* __restrict__ Xb)
{
    const size_t i = (size_t)(blockIdx.x * 256 + threadIdx.x) * 8;
    float4 a0 = *(const float4*)(X + i);
    float4 a1 = *(const float4*)(X + i + 4);
    uint4 pk;
    pk.x = packtr(a0.x, a0.y); pk.y = packtr(a0.z, a0.w);
    pk.z = packtr(a1.x, a1.y); pk.w = packtr(a1.z, a1.w);
    *(uint4*)(Xb + i) = pk;
}

// ---------------------------------------------------------------------------
// Fused transpose of Wq/Wk/Wv: 1024x1024 fp32 -> bf16 (D = S^T), z selects.
// ---------------------------------------------------------------------------
__global__ __launch_bounds__(256) void transp_cvt3(
    const float* __restrict__ Wq, const float* __restrict__ Wk,
    const float* __restrict__ Wv, u16* __restrict__ D)
{
    __shared__ u16 T[64][72];
    const float* S = (blockIdx.z == 0) ? Wq : ((blockIdx.z == 1) ? Wk : Wv);
    u16* Dz = D + (size_t)blockIdx.z * 1024 * 1024;
    const int tid = threadIdx.x;
    const int bx = blockIdx.x, by = blockIdx.y;
#pragma unroll
    for (int i = 0; i < 4; ++i) {
        int id = tid + i * 256;
        int fr = id >> 4, fc = id & 15;
        float4 v = *(const float4*)(S + (size_t)(by * 64 + fr) * 1024 + bx * 64 + fc * 4);
        T[fc * 4 + 0][fr] = f2bf(v.x);
        T[fc * 4 + 1][fr] = f2bf(v.y);
        T[fc * 4 + 2][fr] = f2bf(v.z);
        T[fc * 4 + 3][fr] = f2bf(v.w);
    }
    __syncthreads();
#pragma unroll
    for (int i = 0; i < 2; ++i) {
        int id = tid + i * 256;
        int c = id >> 3, g = id & 7;
        *(uint4*)(Dz + (size_t)(bx * 64 + c) * 1024 + by * 64 + g * 8) = *(const uint4*)&T[c][g * 8];
    }
}

// single-matrix version for Wo
__global__ __launch_bounds__(256) void transp_cvt(
    const float* __restrict__ S, u16* __restrict__ D)
{
    __shared__ u16 T[64][72];
    const int tid = threadIdx.x;
    const int bx = blockIdx.x, by = blockIdx.y;
#pragma unroll
    for (int i = 0; i < 4; ++i) {
        int id = tid + i * 256;
        int fr = id >> 4, fc = id & 15;
        float4 v = *(const float4*)(S + (size_t)(by * 64 + fr) * 1024 + bx * 64 + fc * 4);
        T[fc * 4 + 0][fr] = f2bf(v.x);
        T[fc * 4 + 1][fr] = f2bf(v.y);
        T[fc * 4 + 2][fr] = f2bf(v.z);
        T[fc * 4 + 3][fr] = f2bf(v.w);
    }
    __syncthreads();
#pragma unroll
    for (int i = 0; i < 2; ++i) {
        int id = tid + i * 256;
        int c = id >> 3, g = id & 7;
        *(uint4*)(D + (size_t)(bx * 64 + c) * 1024 + by * 64 + g * 8) = *(const uint4*)&T[c][g * 8];
    }
}

// ---------------------------------------------------------------------------
// QKV = Xb @ [Wq|Wk|Wv]^T(k-major) + FUSED RoPE epilogue. Both operands bf16
// via cp16 (pure m97 structure). 128x128 tile, BK=32, dbuf LDS, one
// barrier/K-step. Epilogue: bx<8 = Q (rope + scale), bx<16 = K (rope).
// ---------------------------------------------------------------------------
__global__ __launch_bounds__(256) void gemm_qkv(
    const u16* __restrict__ A, const u16* __restrict__ Bt, u16* __restrict__ C)
{
    __shared__ u16 As[2][128][32];
    __shared__ u16 Bs[2][128][32];
    const int tid = threadIdx.x;
    const int lane = tid & 63, w = tid >> 6;
    const int col = lane & 15, quad = lane >> 4;
    const int bm = blockIdx.y << 7, bn = blockIdx.x << 7;
    const int wm = (w & 1) << 6, wn = (w >> 1) << 6;
    const int sr = lane >> 2, sc = (lane & 3) << 3;
    const f32x4 zero = {0.f, 0.f, 0.f, 0.f};
    f32x4 acc[4][4];
#pragma unroll
    for (int i = 0; i < 4; ++i)
#pragma unroll
        for (int j = 0; j < 4; ++j) acc[i][j] = zero;

#pragma unroll
    for (int i = 0; i < 2; ++i) {
        const int r0 = w * 32 + i * 16;
        cp16(A  + (size_t)(bm + r0 + sr) * 1024 + sc, &As[0][r0][0]);
        cp16(Bt + (size_t)(bn + r0 + sr) * 1024 + sc, &Bs[0][r0][0]);
    }

    for (int kc = 0; kc < 32; ++kc) {
        const int cur = kc & 1, nxt = cur ^ 1;
        __syncthreads();
        if (kc + 1 < 32) {
            const int k1 = (kc + 1) * 32;
#pragma unroll
            for (int i = 0; i < 2; ++i) {
                const int r0 = w * 32 + i * 16;
                cp16(A  + (size_t)(bm + r0 + sr) * 1024 + k1 + sc, &As[nxt][r0][0]);
                cp16(Bt + (size_t)(bn + r0 + sr) * 1024 + k1 + sc, &Bs[nxt][r0][0]);
            }
        }
        bf16x8 af[4], bfr[4];
#pragma unroll
        for (int i = 0; i < 4; ++i) af[i] = *(const bf16x8*)&As[cur][wm + i * 16 + col][quad * 8];
#pragma unroll
        for (int j = 0; j < 4; ++j) bfr[j] = *(const bf16x8*)&Bs[cur][wn + j * 16 + col][quad * 8];
#pragma unroll
        for (int i = 0; i < 4; ++i)
#pragma unroll
            for (int j = 0; j < 4; ++j)
                acc[i][j] = __builtin_amdgcn_mfma_f32_16x16x32_bf16(af[i], bfr[j], acc[i][j], 0, 0, 0);
    }

    // fused RoPE epilogue (Q and K blocks only)
    if (blockIdx.x < 16) {
        const float scale = (blockIdx.x < 8) ? 0.18033688011112042f : 1.0f;  // Q: (1/8)*log2e
        const float inv0 = __expf((float)col * -0.2878231366242557f);         // irope = col
        const float inv1 = __expf((float)(16 + col) * -0.2878231366242557f);  // irope = 16+col
#pragma unroll
        for (int i = 0; i < 4; ++i)
#pragma unroll
            for (int r = 0; r < 4; ++r) {
                const float t = (float)(bm + wm + i * 16 + quad * 4 + r);
                float s0, c0, s1, c1;
                __sincosf(t * inv0, &s0, &c0);
                __sincosf(t * inv1, &s1, &c1);
                float a0 = acc[i][0][r], b0 = acc[i][2][r];
                acc[i][0][r] = (a0 * c0 - b0 * s0) * scale;
                acc[i][2][r] = (b0 * c0 + a0 * s0) * scale;
                float a1 = acc[i][1][r], b1 = acc[i][3][r];
                acc[i][1][r] = (a1 * c1 - b1 * s1) * scale;
                acc[i][3][r] = (b1 * c1 + a1 * s1) * scale;
            }
    }
#pragma unroll
    for (int i = 0; i < 4; ++i)
#pragma unroll
        for (int j = 0; j < 4; ++j)
#pragma unroll
            for (int r = 0; r < 4; ++r)
                C[(size_t)(bm + wm + i * 16 + quad * 4 + r) * QKVS + bn + wn + j * 16 + col] =
                    f2bf(acc[i][j][r]);
}

// ---------------------------------------------------------------------------
// out = AO @ Wot^T (both bf16 k-major, C fp32). Retiled 128(M)x64(N):
// grid 16x32 = 512 blocks -> 2 blocks/CU. Waves 2x2 covering 64x32 each;
// acc[4][2]; LDS 24 KB.
// ---------------------------------------------------------------------------
__global__ __launch_bounds__(256) void gemm_out(
    const u16* __restrict__ A, const u16* __restrict__ Bt, float* __restrict__ C)
{
    __shared__ u16 As[2][128][32];
    __shared__ u16 Bs[2][64][32];
    const int tid = threadIdx.x;
    const int lane = tid & 63, w = tid >> 6;
    const int col = lane & 15, quad = lane >> 4;
    const int bm = blockIdx.y << 7, bn = blockIdx.x << 6;
    const int wm = (w & 1) << 6, wn = (w >> 1) << 5;
    const int sr = lane >> 2, sc = (lane & 3) << 3;
    const f32x4 zero = {0.f, 0.f, 0.f, 0.f};
    f32x4 acc[4][2];
#pragma unroll
    for (int i = 0; i < 4; ++i)
#pragma unroll
        for (int j = 0; j < 2; ++j) acc[i][j] = zero;

    {
#pragma unroll
        for (int i = 0; i < 2; ++i) {
            const int r0 = w * 32 + i * 16;
            cp16(A + (size_t)(bm + r0 + sr) * 1024 + sc, &As[0][r0][0]);
        }
        cp16(Bt + (size_t)(bn + w * 16 + sr) * 1024 + sc, &Bs[0][w * 16][0]);
    }

    for (int kc = 0; kc < 32; ++kc) {
        const int cur = kc & 1, nxt = cur ^ 1;
        __syncthreads();
        if (kc + 1 < 32) {
            const int k1 = (kc + 1) * 32;
#pragma unroll
            for (int i = 0; i < 2; ++i) {
                const int r0 = w * 32 + i * 16;
                cp16(A + (size_t)(bm + r0 + sr) * 1024 + k1 + sc, &As[nxt][r0][0]);
            }
            cp16(Bt + (size_t)(bn + w * 16 + sr) * 1024 + k1 + sc, &Bs[nxt][w * 16][0]);
        }
        bf16x8 af[4], bfr[2];
#pragma unroll
        for (int i = 0; i < 4; ++i) af[i] = *(const bf16x8*)&As[cur][wm + i * 16 + col][quad * 8];
#pragma unroll
        for (int j = 0; j < 2; ++j) bfr[j] = *(const bf16x8*)&Bs[cur][wn + j * 16 + col][quad * 8];
#pragma unroll
        for (int i = 0; i < 4; ++i)
#pragma unroll
            for (int j = 0; j < 2; ++j)
                acc[i][j] = __builtin_amdgcn_mfma_f32_16x16x32_bf16(af[i], bfr[j], acc[i][j], 0, 0, 0);
    }
#pragma unroll
    for (int i = 0; i < 4; ++i)
#pragma unroll
        for (int j = 0; j < 2; ++j)
#pragma unroll
            for (int r = 0; r < 4; ++r)
                C[(size_t)(bm + wm + i * 16 + quad * 4 + r) * 1024 + bn + wn + j * 16 + col] =
                    acc[i][j][r];
}

// ---------------------------------------------------------------------------
// MFMA flash attention v9 (round-5/7 version, verbatim — best measured 86.4us):
//  * cperm Vt single-buffered [64][136] (pad -> 4-bank row rotation),
//    Ks dbuf XOR-swizzled; LDS 50176 B. 256 threads, VGPR 100 (no spill).
//  * K=32 PV (40 full-rate MFMAs), ks-outer S, setprio around MFMA bursts.
//  * Two cheap barriers/chunk; K prefetch via cp16 stays in flight across
//    the compute phase.
//  * Constraint set proven over r3-r11: no atomics / no device fences /
//    no cross-block reads (L2 poison); no 1024-thread blocks (64-VGPR cap
//    forces spill); makespan = 32-chunk chain x ~6560cyc is the structural
//    floor of this pipeline at <=512 threads/block.
// ---------------------------------------------------------------------------
__global__ __launch_bounds__(256) void attn_mfma(
    const u16* __restrict__ QKV, u16* __restrict__ AO)
{
    __shared__ u16 Ks[2][128][64];   // [key][dim], unpadded, XOR-swizzled 16B blocks
    __shared__ u16 Vt[64][136];      // [dim][cperm(key)] single-buffered + 8-u16 pad
    const int bid = blockIdx.x;
    int h, qt;
    if (bid < 256) { h = 8 + (bid & 7); qt = bid >> 3; }           // diff: 32 chunks
    else { int i = bid - 256; h = i & 7; qt = 31 - (i >> 3); }     // causal desc qt
    const bool causal = (h < NAR);
    const int tid = threadIdx.x;
    const int w = tid >> 6, lane = tid & 63;
    const int col = lane & 15, quad = lane >> 4;
    const int qb = qt * 128;
    const int qr0 = qb + w * 32 + col;
    const int qr1 = qr0 + 16;
    // column-permuted position of key a=2*lane (a's pair b=a+1 sits at cva+1)
    const int cva = ((lane >> 1) & 3) * 32 + (lane >> 3) * 4 + (lane & 1) * 2;

    // hoisted Q B-frags (rope'd, pre-scaled by 0.125*log2e in gemm_qkv)
    bf16x8 qf[2][2];
#pragma unroll
    for (int s = 0; s < 2; ++s)
#pragma unroll
        for (int ks = 0; ks < 2; ++ks)
            qf[s][ks] = *(const bf16x8*)(QKV + (size_t)(qr0 + s * 16) * QKVS +
                                         h * DHEAD + ks * 32 + quad * 8);

    bf16x8 ones8;
#pragma unroll
    for (int i = 0; i < 8; ++i) ones8[i] = (short)0x3F80;

    const f32x4 zero = {0.f, 0.f, 0.f, 0.f};
    f32x4 O[2][5];  // [set][nd] O^T tiles (d = nd*16+quad*4+r, q = col); nd=4 = l
#pragma unroll
    for (int s = 0; s < 2; ++s)
#pragma unroll
        for (int nd = 0; nd < 5; ++nd) O[s][nd] = zero;

    const int nch = causal ? (qt + 1) : (LSEQ / 128);
    const int krow = lane >> 3;
    const int kcb = (lane & 7) ^ krow;
    const u16* kbase = QKV + (size_t)krow * QKVS + 1024 + h * DHEAD + kcb * 8;
    const u16* vbase = QKV + (size_t)(lane * 2) * QKVS + 2048 + h * DHEAD + w * 16;

    u32x4 vA0, vA1, vB0, vB1;   // pending V(ch) regs for end-of-iter Vt write
    bf16x8 pf8[2][4];           // P(ch) frags: pf8[s][tp] = keys 32tp..32tp+31 (permuted)

#define VT_WRITE()                                                                                 \
    _Pragma("unroll")                                                                              \
    for (int j = 0; j < 4; ++j) {                                                                  \
        *(u32*)&Vt[w * 16 + 2 * j][cva]         = __builtin_amdgcn_perm(vB0[j], vA0[j], 0x05040100u); \
        *(u32*)&Vt[w * 16 + 2 * j + 1][cva]     = __builtin_amdgcn_perm(vB0[j], vA0[j], 0x07060302u); \
        *(u32*)&Vt[w * 16 + 8 + 2 * j][cva]     = __builtin_amdgcn_perm(vB1[j], vA1[j], 0x05040100u); \
        *(u32*)&Vt[w * 16 + 8 + 2 * j + 1][cva] = __builtin_amdgcn_perm(vB1[j], vA1[j], 0x07060302u); \
    }

// PV burst over Vt at K=32: tp-outer, l-row folded in -> acc reuse distance 10.
#define PV_STEP()                                                                                  \
    {                                                                                              \
        __builtin_amdgcn_s_setprio(1);                                                             \
        _Pragma("unroll")                                                                          \
        for (int tp = 0; tp < 4; ++tp) {                                                           \
            bf16x8 vv[4];                                                                          \
            _Pragma("unroll")                                                                      \
            for (int nd = 0; nd < 4; ++nd)                                                         \
                vv[nd] = *(const bf16x8*)&Vt[nd * 16 + col][quad * 32 + tp * 8];                   \
            _Pragma("unroll")                                                                      \
            for (int nd = 0; nd < 4; ++nd) {                                                       \
                O[0][nd] = __builtin_amdgcn_mfma_f32_16x16x32_bf16(vv[nd], pf8[0][tp], O[0][nd], 0, 0, 0); \
                O[1][nd] = __builtin_amdgcn_mfma_f32_16x16x32_bf16(vv[nd], pf8[1][tp], O[1][nd], 0, 0, 0); \
            }                                                                                      \
            O[0][4] = __builtin_amdgcn_mfma_f32_16x16x32_bf16(ones8, pf8[0][tp], O[0][4], 0, 0, 0); \
            O[1][4] = __builtin_amdgcn_mfma_f32_16x16x32_bf16(ones8, pf8[1][tp], O[1][4], 0, 0, 0); \
        }                                                                                          \
        __builtin_amdgcn_s_setprio(0);                                                             \
    }

// S(CH) + exp -> pf8. ks-outer: st[s][jj] reuse distance 8.
#define S_STEP(KBUF, CH)                                                                           \
    {                                                                                              \
        const bool mask = causal && ((CH) == qt);                                                  \
        _Pragma("unroll")                                                                          \
        for (int hf = 0; hf < 2; ++hf) {                                                           \
            f32x4 st[2][4];                                                                        \
            _Pragma("unroll")                                                                      \
            for (int s = 0; s < 2; ++s)                                                            \
                _Pragma("unroll")                                                                  \
                for (int jj = 0; jj < 4; ++jj) st[s][jj] = zero;                                   \
            __builtin_amdgcn_s_setprio(1);                                                         \
            _Pragma("unroll")                                                                      \
            for (int ks = 0; ks < 2; ++ks)                                                         \
                _Pragma("unroll")                                                                  \
                for (int jj = 0; jj < 4; ++jj) {                                                   \
                    bf16x8 kf = *(const bf16x8*)&Ks[KBUF][(hf * 4 + jj) * 16 + col]                \
                                                         [((ks * 4 + quad) ^ (col & 7)) * 8];      \
                    st[0][jj] = __builtin_amdgcn_mfma_f32_16x16x32_bf16(kf, qf[0][ks], st[0][jj], 0, 0, 0); \
                    st[1][jj] = __builtin_amdgcn_mfma_f32_16x16x32_bf16(kf, qf[1][ks], st[1][jj], 0, 0, 0); \
                }                                                                                  \
            __builtin_amdgcn_s_setprio(0);                                                         \
            if (mask) {                                                                            \
                _Pragma("unroll")                                                                  \
                for (int jj = 0; jj < 4; ++jj) {                                                   \
                    const int kk = (CH) * 128 + (hf * 4 + jj) * 16 + quad * 4;                     \
                    _Pragma("unroll")                                                              \
                    for (int r = 0; r < 4; ++r) {                                                  \
                        if (kk + r > qr0) st[0][jj][r] = -1e30f;                                   \
                        if (kk + r > qr1) st[1][jj][r] = -1e30f;                                   \
                    }                                                                              \
                }                                                                                  \
            }                                                                                      \
            _Pragma("unroll")                                                                      \
            for (int s = 0; s < 2; ++s)                                                            \
                _Pragma("unroll")                                                                  \
                for (int jj = 0; jj < 4; ++jj) {                                                   \
                    u32 plo = packtr(__builtin_amdgcn_exp2f(st[s][jj][0]),                         \
                                     __builtin_amdgcn_exp2f(st[s][jj][1]));                        \
                    u32 phi = packtr(__builtin_amdgcn_exp2f(st[s][jj][2]),                         \
                                     __builtin_amdgcn_exp2f(st[s][jj][3]));                        \
                    u32* p = (u32*)&pf8[s][0] + (hf * 4 + jj) * 2;                                 \
                    p[0] = plo; p[1] = phi;                                                        \
                }                                                                                  \
        }                                                                                          \
    }

    // ---- prologue: stage chunk 0 ----
#pragma unroll
    for (int i = 0; i < 4; ++i)
        cp16(kbase + (size_t)((i * 4 + w) * 8) * QKVS, &Ks[0][(i * 4 + w) * 8][0]);
    vA0 = *(u32x4*)(vbase);
    vA1 = *(u32x4*)(vbase + 8);
    vB0 = *(u32x4*)(vbase + QKVS);
    vB1 = *(u32x4*)(vbase + QKVS + 8);
    __syncthreads();  // K(0) in LDS, V(0) in regs
    VT_WRITE();       // Vt <- V(0); visibility via barrier_a of iter 1 (or tail)
    if (nch > 1) {    // prefetch K(1); drained at barrier_a of iter 1
#pragma unroll
        for (int i = 0; i < 4; ++i)
            cp16(kbase + (size_t)(128 + (i * 4 + w) * 8) * QKVS, &Ks[1][(i * 4 + w) * 8][0]);
    }
    // S(0) + exp -> pf8
    S_STEP(0, 0);

    // ---- main loop ----
    for (int ch = 1; ch < nch; ++ch) {
        const int cur = ch & 1;
        __syncthreads();  // barrier_a: Ks[cur]=K(ch) drained; Vt=V(ch-1) visible
        if (ch + 1 < nch) {  // prefetch K(ch+1) into the buffer S(ch) is NOT reading
            const size_t c1 = (size_t)(ch + 1) * 128;
#pragma unroll
            for (int i = 0; i < 4; ++i)
                cp16(kbase + (c1 + (i * 4 + w) * 8) * QKVS, &Ks[cur ^ 1][(i * 4 + w) * 8][0]);
        }
        {   // V(ch) regs for end-of-iter Vt write
            const u16* vp = vbase + (size_t)ch * 128 * QKVS;
            vA0 = *(u32x4*)(vp);
            vA1 = *(u32x4*)(vp + 8);
            vB0 = *(u32x4*)(vp + QKVS);
            vB1 = *(u32x4*)(vp + QKVS + 8);
        }
        PV_STEP();        // P(ch-1) x V(ch-1)
        S_STEP(cur, ch);  // -> pf8 = P(ch)
        __syncthreads();  // barrier_b: all PV reads done; loads above drained
        VT_WRITE();       // Vt <- V(ch)
    }

    // ---- tail: PV(nch-1) ----
    __syncthreads();  // Vt = V(nch-1) visible (prologue write if nch==1)
    PV_STEP();

    // epilogue: l already in this lane (col=q); O^T rows d = nd*16+quad*4+r
#pragma unroll
    for (int s = 0; s < 2; ++s) {
        const float inv = 1.f / O[s][4][0];
        const int qrow = qr0 + s * 16;
#pragma unroll
        for (int nd = 0; nd < 4; ++nd) {
            ushort4 ov;
            ov.x = f2bf(O[s][nd][0] * inv);
            ov.y = f2bf(O[s][nd][1] * inv);
            ov.z = f2bf(O[s][nd][2] * inv);
            ov.w = f2bf(O[s][nd][3] * inv);
            *(ushort4*)(AO + (size_t)qrow * 1024 + h * DHEAD + nd * 16 + quad * 4) = ov;
        }
    }
#undef VT_WRITE
#undef PV_STEP
#undef S_STEP
}

// ---------------------------------------------------------------------------
extern "C" void kernel_launch(void* const* d_in, const int* in_sizes, int n_in,
                              void* d_out, int out_size, void* d_ws, size_t ws_size,
                              hipStream_t stream)
{
    const float* X  = (const float*)d_in[0];
    const float* Wq = (const float*)d_in[1];
    const float* Wk = (const float*)d_in[2];
    const float* Wv = (const float*)d_in[3];
    const float* Wo = (const float*)d_in[4];
    float* out = (float*)d_out;

    // ws (u16 units), liveness overlays:
    //   [0 .. 4M):   Wqkvt [3072][1024] (dead after gemm_qkv) -> AOb [4096][1024]
    //   [4M .. 16M): QKV [4096][3072] (dead after attn) -> Wot [1024][1024]
    // d_out: Xb (bf16 X, 8 MB) during xcast..gemm_qkv; final out after gemm_out.
    u16* Wt  = (u16*)d_ws;
    u16* AOb = (u16*)d_ws;
    u16* QKV = (u16*)d_ws + (size_t)4 * 1024 * 1024;
    u16* Wot = QKV;
    u16* Xb  = (u16*)out;

    xcast<<<2048, 256, 0, stream>>>(X, Xb);
    transp_cvt3<<<dim3(16, 16, 3), 256, 0, stream>>>(Wq, Wk, Wv, Wt);
    gemm_qkv<<<dim3(24, 32), 256, 0, stream>>>(Xb, Wt, QKV);  // rope fused in epilogue
    attn_mfma<<<512, 256, 0, stream>>>(QKV, AOb);
    transp_cvt<<<dim3(16, 16), 256, 0, stream>>>(Wo, Wot);    // QKV dead now
    gemm_out<<<dim3(16, 32), 256, 0, stream>>>(AOb, Wot, out); // overwrites Xb
}